// Round 1
// baseline (337.313 us; speedup 1.0000x reference)
//
#include <hip/hip_runtime.h>
#include <stdint.h>

typedef short bf16x8 __attribute__((ext_vector_type(8)));
typedef float f32x4 __attribute__((ext_vector_type(4)));

__device__ __forceinline__ unsigned short f2bf(float f) {
  unsigned int u = __builtin_bit_cast(unsigned int, f);
  u += 0x7fffu + ((u >> 16) & 1u);
  return (unsigned short)(u >> 16);
}

__device__ __forceinline__ void gload_lds16(const void* g, void* l) {
  __builtin_amdgcn_global_load_lds(
      (const __attribute__((address_space(1))) unsigned int*)g,
      (__attribute__((address_space(3))) unsigned int*)l, 16, 0, 0);
}

// ---------------- elementwise f32 -> bf16 ----------------
__global__ __launch_bounds__(256) void cvt_f32_bf16(const float* __restrict__ in,
                                                    unsigned short* __restrict__ out, int n4) {
  int i = blockIdx.x * blockDim.x + threadIdx.x;
  int stride = gridDim.x * blockDim.x;
  for (; i < n4; i += stride) {
    float4 v = ((const float4*)in)[i];
    ushort4 o;
    o.x = f2bf(v.x); o.y = f2bf(v.y); o.z = f2bf(v.z); o.w = f2bf(v.w);
    ((ushort4*)out)[i] = o;
  }
}

// ---------------- transpose + convert f32[R][C] -> bf16[C][R] ----------------
__global__ __launch_bounds__(256) void transpose_cvt(const float* __restrict__ in,
                                                     unsigned short* __restrict__ out,
                                                     int R, int C) {
  __shared__ unsigned short t[64][65];
  int c0 = blockIdx.x * 64, r0 = blockIdx.y * 64;
  int tid = threadIdx.x;
#pragma unroll
  for (int i = 0; i < 16; ++i) {
    int idx = tid + i * 256;
    int rr = idx >> 6, cc = idx & 63;
    t[rr][cc] = f2bf(in[(size_t)(r0 + rr) * C + c0 + cc]);
  }
  __syncthreads();
#pragma unroll
  for (int i = 0; i < 16; ++i) {
    int idx = tid + i * 256;
    int rr = idx >> 6, cc = idx & 63;
    out[(size_t)(c0 + rr) * R + r0 + cc] = t[cc][rr];
  }
}

// ---------------- batched transpose bf16[z][R][C] -> bf16[z][C][R] ----------------
__global__ __launch_bounds__(256) void transpose_b16(const unsigned short* __restrict__ in,
                                                     unsigned short* __restrict__ out,
                                                     int R, int C) {
  __shared__ unsigned short t[64][65];
  const unsigned short* ip = in + (size_t)blockIdx.z * R * C;
  unsigned short* op = out + (size_t)blockIdx.z * R * C;
  int c0 = blockIdx.x * 64, r0 = blockIdx.y * 64;
  int tid = threadIdx.x;
#pragma unroll
  for (int i = 0; i < 16; ++i) {
    int idx = tid + i * 256;
    int rr = idx >> 6, cc = idx & 63;
    t[rr][cc] = ip[(size_t)(r0 + rr) * C + c0 + cc];
  }
  __syncthreads();
#pragma unroll
  for (int i = 0; i < 16; ++i) {
    int idx = tid + i * 256;
    int rr = idx >> 6, cc = idx & 63;
    op[(size_t)(c0 + rr) * R + r0 + cc] = t[cc][rr];
  }
}

// ---------------- GEMM1: qkv = hs @ W + b, scatter to q/k/v [B,H,S,D] bf16 ----------------
// A [8192,1024] bf16 row-major, Bt [3072,1024] bf16 (= W^T)
__global__ __launch_bounds__(256) void gemm_qkv(const unsigned short* __restrict__ A,
                                                const unsigned short* __restrict__ Bt,
                                                const float* __restrict__ bias,
                                                unsigned short* __restrict__ qb,
                                                unsigned short* __restrict__ kb,
                                                unsigned short* __restrict__ vb) {
  __shared__ char smem[16384];
  char* As = smem;
  char* Bs = smem + 8192;
  const int tid = threadIdx.x;
  const int wid = tid >> 6, lane = tid & 63;
  const int g = lane >> 4, r = lane & 15;
  const int wr = wid >> 1, wc = wid & 1;
  const int bn = blockIdx.x, bm = blockIdx.y;
  f32x4 acc[4][4] = {};
  const unsigned short* Arow = A + (size_t)(bm * 128) * 1024;
  const unsigned short* Brow = Bt + (size_t)(bn * 128) * 1024;
  for (int k0 = 0; k0 < 1024; k0 += 32) {
#pragma unroll
    for (int c = 0; c < 2; ++c) {
      int ob = wid * 2048 + c * 1024 + lane * 16;
      int row = ob >> 6;
      int colB = ob & 63;
      gload_lds16(Arow + (size_t)row * 1024 + k0 + (colB >> 1), As + wid * 2048 + c * 1024);
      gload_lds16(Brow + (size_t)row * 1024 + k0 + (colB >> 1), Bs + wid * 2048 + c * 1024);
    }
    __syncthreads();
    bf16x8 a[4], b[4];
#pragma unroll
    for (int m = 0; m < 4; ++m)
      a[m] = *(const bf16x8*)(As + ((wr * 64 + m * 16 + r) * 64 + g * 16));
#pragma unroll
    for (int n = 0; n < 4; ++n)
      b[n] = *(const bf16x8*)(Bs + ((wc * 64 + n * 16 + r) * 64 + g * 16));
#pragma unroll
    for (int m = 0; m < 4; ++m)
#pragma unroll
      for (int n = 0; n < 4; ++n)
        acc[m][n] = __builtin_amdgcn_mfma_f32_16x16x32_bf16(a[m], b[n], acc[m][n], 0, 0, 0);
    __syncthreads();
  }
  const int colbase = bn * 128 + wc * 64;
  const int rowbase = bm * 128 + wr * 64;
  const int sec = colbase >> 10;  // 0=q 1=k 2=v, uniform per block
#pragma unroll
  for (int m = 0; m < 4; ++m) {
#pragma unroll
    for (int n = 0; n < 4; ++n) {
#pragma unroll
      for (int reg = 0; reg < 4; ++reg) {
        int gm = rowbase + m * 16 + g * 4 + reg;
        int gn = colbase + n * 16 + r;
        float val = acc[m][n][reg] + bias[gn];
        int bb = gm >> 11, s = gm & 2047;
        int hc = gn & 1023;
        int h = hc >> 6, d = hc & 63;
        size_t oidx = (((size_t)(bb * 16 + h)) * 2048 + s) * 64 + d;
        if (sec == 0) qb[oidx] = f2bf(val * 0.125f);       // fold 1/sqrt(64)
        else if (sec == 1) kb[oidx] = f2bf(val);
        else vb[oidx] = f2bf(val);
      }
    }
  }
}

// ---------------- GEMM2: out = attn_out @ Wp + b (f32 out) ----------------
__global__ __launch_bounds__(256) void gemm_proj(const unsigned short* __restrict__ A,
                                                 const unsigned short* __restrict__ Bt,
                                                 const float* __restrict__ bias,
                                                 float* __restrict__ out) {
  __shared__ char smem[16384];
  char* As = smem;
  char* Bs = smem + 8192;
  const int tid = threadIdx.x;
  const int wid = tid >> 6, lane = tid & 63;
  const int g = lane >> 4, r = lane & 15;
  const int wr = wid >> 1, wc = wid & 1;
  const int bn = blockIdx.x, bm = blockIdx.y;
  f32x4 acc[4][4] = {};
  const unsigned short* Arow = A + (size_t)(bm * 128) * 1024;
  const unsigned short* Brow = Bt + (size_t)(bn * 128) * 1024;
  for (int k0 = 0; k0 < 1024; k0 += 32) {
#pragma unroll
    for (int c = 0; c < 2; ++c) {
      int ob = wid * 2048 + c * 1024 + lane * 16;
      int row = ob >> 6;
      int colB = ob & 63;
      gload_lds16(Arow + (size_t)row * 1024 + k0 + (colB >> 1), As + wid * 2048 + c * 1024);
      gload_lds16(Brow + (size_t)row * 1024 + k0 + (colB >> 1), Bs + wid * 2048 + c * 1024);
    }
    __syncthreads();
    bf16x8 a[4], b[4];
#pragma unroll
    for (int m = 0; m < 4; ++m)
      a[m] = *(const bf16x8*)(As + ((wr * 64 + m * 16 + r) * 64 + g * 16));
#pragma unroll
    for (int n = 0; n < 4; ++n)
      b[n] = *(const bf16x8*)(Bs + ((wc * 64 + n * 16 + r) * 64 + g * 16));
#pragma unroll
    for (int m = 0; m < 4; ++m)
#pragma unroll
      for (int n = 0; n < 4; ++n)
        acc[m][n] = __builtin_amdgcn_mfma_f32_16x16x32_bf16(a[m], b[n], acc[m][n], 0, 0, 0);
    __syncthreads();
  }
  const int colbase = bn * 128 + wc * 64;
  const int rowbase = bm * 128 + wr * 64;
#pragma unroll
  for (int m = 0; m < 4; ++m) {
#pragma unroll
    for (int n = 0; n < 4; ++n) {
#pragma unroll
      for (int reg = 0; reg < 4; ++reg) {
        int gm = rowbase + m * 16 + g * 4 + reg;
        int gn = colbase + n * 16 + r;
        out[(size_t)gm * 1024 + gn] = acc[m][n][reg] + bias[gn];
      }
    }
  }
}

// ---------------- flash attention: q [B,H,S,D], k [B,H,S,D], vt [B,H,D,S] -> aout [B*S, E] bf16
__global__ __launch_bounds__(256) void attn_kernel(const unsigned short* __restrict__ qb,
                                                   const unsigned short* __restrict__ kb,
                                                   const unsigned short* __restrict__ vtb,
                                                   unsigned short* __restrict__ aout) {
  __shared__ char smem[32768];
  char* Kt = smem;            // [64 kv][64 d] bf16, xor-swizzled
  char* Vt = smem + 8192;     // [64 d][64 kv] bf16, xor-swizzled
  const int tid = threadIdx.x;
  const int wid = tid >> 6, lane = tid & 63;
  const int g = lane >> 4, r = lane & 15;
  const int qt = blockIdx.x, bh = blockIdx.y;
  char* Pl = smem + 16384 + wid * 4096;  // per-wave P [32][64] bf16, xor-swizzled
  const unsigned short* qbase = qb + (size_t)bh * 2048 * 64;
  const unsigned short* kbh = kb + (size_t)bh * 2048 * 64;
  const unsigned short* vbh = vtb + (size_t)bh * 64 * 2048;
  const int qrow0 = qt * 128 + wid * 32;

  bf16x8 aq[2][2];
#pragma unroll
  for (int mf = 0; mf < 2; ++mf)
#pragma unroll
    for (int ks = 0; ks < 2; ++ks)
      aq[mf][ks] = *(const bf16x8*)(qbase + (size_t)(qrow0 + mf * 16 + r) * 64 + ks * 32 + g * 8);

  f32x4 o[2][4] = {};
  float mrow[2][4], lrow[2][4];
#pragma unroll
  for (int mf = 0; mf < 2; ++mf)
#pragma unroll
    for (int reg = 0; reg < 4; ++reg) { mrow[mf][reg] = -1e30f; lrow[mf][reg] = 0.f; }

  const int nkv = (qt + 1) * 2;
  for (int kt = 0; kt < nkv; ++kt) {
    const int kv0 = kt * 64;
    // stage K tile [64][64] and VT tile [64][64]; pre-swizzled global source,
    // linear LDS dest (global_load_lds writes base + lane*16)
#pragma unroll
    for (int c = 0; c < 2; ++c) {
      int ob = wid * 2048 + c * 1024 + lane * 16;
      int row = ob >> 7;          // 128B per row
      int slot = (ob >> 4) & 7;
      int ss = slot ^ (row & 7);
      gload_lds16(kbh + ((size_t)(kv0 + row)) * 64 + ss * 8, Kt + wid * 2048 + c * 1024);
      gload_lds16(vbh + (size_t)row * 2048 + kv0 + ss * 8, Vt + wid * 2048 + c * 1024);
    }
    __syncthreads();

    // scores: s[q][kv] = sum_d Q[q,d] K[kv,d]
    f32x4 s[2][4] = {};
#pragma unroll
    for (int ks = 0; ks < 2; ++ks) {
      bf16x8 bk[4];
#pragma unroll
      for (int nb = 0; nb < 4; ++nb) {
        int kv = nb * 16 + r;
        int slot = (ks * 4 + g) ^ (kv & 7);
        bk[nb] = *(const bf16x8*)(Kt + kv * 128 + slot * 16);
      }
#pragma unroll
      for (int mf = 0; mf < 2; ++mf)
#pragma unroll
        for (int nb = 0; nb < 4; ++nb)
          s[mf][nb] = __builtin_amdgcn_mfma_f32_16x16x32_bf16(aq[mf][ks], bk[nb], s[mf][nb], 0, 0, 0);
    }

    // causal mask (only the two diagonal-adjacent tiles need it)
    if (kt >= 2 * qt) {
#pragma unroll
      for (int mf = 0; mf < 2; ++mf)
#pragma unroll
        for (int nb = 0; nb < 4; ++nb)
#pragma unroll
          for (int reg = 0; reg < 4; ++reg) {
            int qg = qrow0 + mf * 16 + g * 4 + reg;
            int kg = kv0 + nb * 16 + r;
            s[mf][nb][reg] = (kg > qg) ? -1e30f : s[mf][nb][reg];
          }
    }

    // online softmax; row = (lane>>4)*4+reg lives in one 16-lane group
    float p[2][4][4];
#pragma unroll
    for (int mf = 0; mf < 2; ++mf)
#pragma unroll
      for (int reg = 0; reg < 4; ++reg) {
        float tm = s[mf][0][reg];
#pragma unroll
        for (int nb = 1; nb < 4; ++nb) tm = fmaxf(tm, s[mf][nb][reg]);
#pragma unroll
        for (int off = 1; off < 16; off <<= 1) tm = fmaxf(tm, __shfl_xor(tm, off));
        float mn = fmaxf(mrow[mf][reg], tm);
        float sc = __expf(mrow[mf][reg] - mn);
        float rs = 0.f;
#pragma unroll
        for (int nb = 0; nb < 4; ++nb) {
          float pv = __expf(s[mf][nb][reg] - mn);
          p[mf][nb][reg] = pv;
          rs += pv;
        }
#pragma unroll
        for (int off = 1; off < 16; off <<= 1) rs += __shfl_xor(rs, off);
        lrow[mf][reg] = lrow[mf][reg] * sc + rs;
        mrow[mf][reg] = mn;
#pragma unroll
        for (int db = 0; db < 4; ++db) o[mf][db][reg] *= sc;
      }

    // P -> per-wave LDS (swizzled), then PV
#pragma unroll
    for (int mf = 0; mf < 2; ++mf)
#pragma unroll
      for (int nb = 0; nb < 4; ++nb)
#pragma unroll
        for (int reg = 0; reg < 4; ++reg) {
          int row = mf * 16 + g * 4 + reg;
          int col = nb * 16 + r;
          int byte = (row * 128 + col * 2) ^ ((row & 7) << 4);
          *(unsigned short*)(Pl + byte) = f2bf(p[mf][nb][reg]);
        }
    asm volatile("s_waitcnt lgkmcnt(0)" ::: "memory");
#pragma unroll
    for (int ks = 0; ks < 2; ++ks) {
      bf16x8 pa[2], bv[4];
#pragma unroll
      for (int mf = 0; mf < 2; ++mf) {
        int row = mf * 16 + r;
        int slot = (ks * 4 + g) ^ (row & 7);
        pa[mf] = *(const bf16x8*)(Pl + row * 128 + slot * 16);
      }
#pragma unroll
      for (int db = 0; db < 4; ++db) {
        int d = db * 16 + r;
        int slot = (ks * 4 + g) ^ (d & 7);
        bv[db] = *(const bf16x8*)(Vt + d * 128 + slot * 16);
      }
#pragma unroll
      for (int mf = 0; mf < 2; ++mf)
#pragma unroll
        for (int db = 0; db < 4; ++db)
          o[mf][db] = __builtin_amdgcn_mfma_f32_16x16x32_bf16(pa[mf], bv[db], o[mf][db], 0, 0, 0);
    }
    __syncthreads();
  }

  // normalize and write merged-head output [B*S, E] bf16
  const int b_ = bh >> 4, h = bh & 15;
#pragma unroll
  for (int mf = 0; mf < 2; ++mf) {
#pragma unroll
    for (int reg = 0; reg < 4; ++reg) {
      float inv = 1.f / lrow[mf][reg];
      int rowg = b_ * 2048 + qrow0 + mf * 16 + g * 4 + reg;
#pragma unroll
      for (int db = 0; db < 4; ++db) {
        int colg = h * 64 + db * 16 + r;
        aout[(size_t)rowg * 1024 + colg] = f2bf(o[mf][db][reg] * inv);
      }
    }
  }
}

extern "C" void kernel_launch(void* const* d_in, const int* in_sizes, int n_in,
                              void* d_out, int out_size, void* d_ws, size_t ws_size,
                              hipStream_t stream) {
  const float* hs = (const float*)d_in[0];      // [4,2048,1024]
  const float* w_attn = (const float*)d_in[1];  // [1024,3072]
  const float* b_attn = (const float*)d_in[2];  // [3072]
  const float* w_proj = (const float*)d_in[3];  // [1024,1024]
  const float* b_proj = (const float*)d_in[4];  // [1024]
  float* out = (float*)d_out;                   // [4,2048,1024] f32
  char* ws = (char*)d_ws;
  size_t off = 0;
  auto alloc = [&](size_t sz) {
    char* p = ws + off;
    off = (off + sz + 255) & ~(size_t)255;
    return p;
  };
  unsigned short* hs_bf = (unsigned short*)alloc((size_t)8192 * 1024 * 2);
  unsigned short* wattnT = (unsigned short*)alloc((size_t)3072 * 1024 * 2);
  unsigned short* wprojT = (unsigned short*)alloc((size_t)1024 * 1024 * 2);
  unsigned short* qb = (unsigned short*)alloc((size_t)8192 * 1024 * 2);
  unsigned short* kb = (unsigned short*)alloc((size_t)8192 * 1024 * 2);
  unsigned short* vb = (unsigned short*)alloc((size_t)8192 * 1024 * 2);
  unsigned short* vtb = (unsigned short*)alloc((size_t)8192 * 1024 * 2);
  unsigned short* aout = hs_bf;  // hs_bf dead after gemm_qkv; reuse

  cvt_f32_bf16<<<2048, 256, 0, stream>>>(hs, hs_bf, 8192 * 1024 / 4);
  transpose_cvt<<<dim3(48, 16), 256, 0, stream>>>(w_attn, wattnT, 1024, 3072);
  transpose_cvt<<<dim3(16, 16), 256, 0, stream>>>(w_proj, wprojT, 1024, 1024);
  gemm_qkv<<<dim3(24, 64), 256, 0, stream>>>(hs_bf, wattnT, b_attn, qb, kb, vb);
  transpose_b16<<<dim3(1, 32, 64), 256, 0, stream>>>(vb, vtb, 2048, 64);
  attn_kernel<<<dim3(16, 64), 256, 0, stream>>>(qb, kb, vtb, aout);
  gemm_proj<<<dim3(8, 64), 256, 0, stream>>>(aout, wprojT, b_proj, out);
}

// Round 2
// 256.709 us; speedup vs baseline: 1.3140x; 1.3140x over previous
//
#include <hip/hip_runtime.h>
#include <stdint.h>

typedef short bf16x8 __attribute__((ext_vector_type(8)));
typedef float f32x4 __attribute__((ext_vector_type(4)));

__device__ __forceinline__ unsigned short f2bf(float f) {
  unsigned int u = __builtin_bit_cast(unsigned int, f);
  u += 0x7fffu + ((u >> 16) & 1u);
  return (unsigned short)(u >> 16);
}

__device__ __forceinline__ void gload_lds16(const void* g, void* l) {
  __builtin_amdgcn_global_load_lds(
      (const __attribute__((address_space(1))) unsigned int*)g,
      (__attribute__((address_space(3))) unsigned int*)l, 16, 0, 0);
}

// ---------------- elementwise f32 -> bf16 ----------------
__global__ __launch_bounds__(256) void cvt_f32_bf16(const float* __restrict__ in,
                                                    unsigned short* __restrict__ out, int n4) {
  int i = blockIdx.x * blockDim.x + threadIdx.x;
  int stride = gridDim.x * blockDim.x;
  for (; i < n4; i += stride) {
    float4 v = ((const float4*)in)[i];
    ushort4 o;
    o.x = f2bf(v.x); o.y = f2bf(v.y); o.z = f2bf(v.z); o.w = f2bf(v.w);
    ((ushort4*)out)[i] = o;
  }
}

// ---------------- transpose + convert f32[R][C] -> bf16[C][R] ----------------
__global__ __launch_bounds__(256) void transpose_cvt(const float* __restrict__ in,
                                                     unsigned short* __restrict__ out,
                                                     int R, int C) {
  __shared__ unsigned short t[64][65];
  int c0 = blockIdx.x * 64, r0 = blockIdx.y * 64;
  int tid = threadIdx.x;
#pragma unroll
  for (int i = 0; i < 16; ++i) {
    int idx = tid + i * 256;
    int rr = idx >> 6, cc = idx & 63;
    t[rr][cc] = f2bf(in[(size_t)(r0 + rr) * C + c0 + cc]);
  }
  __syncthreads();
#pragma unroll
  for (int i = 0; i < 16; ++i) {
    int idx = tid + i * 256;
    int rr = idx >> 6, cc = idx & 63;
    out[(size_t)(c0 + rr) * R + r0 + cc] = t[cc][rr];
  }
}

// ---------------- batched transpose bf16[z][R][C] -> bf16[z][C][R] ----------------
__global__ __launch_bounds__(256) void transpose_b16(const unsigned short* __restrict__ in,
                                                     unsigned short* __restrict__ out,
                                                     int R, int C) {
  __shared__ unsigned short t[64][65];
  const unsigned short* ip = in + (size_t)blockIdx.z * R * C;
  unsigned short* op = out + (size_t)blockIdx.z * R * C;
  int c0 = blockIdx.x * 64, r0 = blockIdx.y * 64;
  int tid = threadIdx.x;
#pragma unroll
  for (int i = 0; i < 16; ++i) {
    int idx = tid + i * 256;
    int rr = idx >> 6, cc = idx & 63;
    t[rr][cc] = ip[(size_t)(r0 + rr) * C + c0 + cc];
  }
  __syncthreads();
#pragma unroll
  for (int i = 0; i < 16; ++i) {
    int idx = tid + i * 256;
    int rr = idx >> 6, cc = idx & 63;
    op[(size_t)(c0 + rr) * R + r0 + cc] = t[cc][rr];
  }
}

// ---------------- GEMM1: qkv = hs @ W + b, scatter to q/k/v [B,H,S,D] bf16 ----------------
__global__ __launch_bounds__(256) void gemm_qkv(const unsigned short* __restrict__ A,
                                                const unsigned short* __restrict__ Bt,
                                                const float* __restrict__ bias,
                                                unsigned short* __restrict__ qb,
                                                unsigned short* __restrict__ kb,
                                                unsigned short* __restrict__ vb) {
  __shared__ char smem[16384];
  char* As = smem;
  char* Bs = smem + 8192;
  const int tid = threadIdx.x;
  const int wid = tid >> 6, lane = tid & 63;
  const int g = lane >> 4, r = lane & 15;
  const int wr = wid >> 1, wc = wid & 1;
  const int bn = blockIdx.x, bm = blockIdx.y;
  f32x4 acc[4][4] = {};
  const unsigned short* Arow = A + (size_t)(bm * 128) * 1024;
  const unsigned short* Brow = Bt + (size_t)(bn * 128) * 1024;
  for (int k0 = 0; k0 < 1024; k0 += 32) {
#pragma unroll
    for (int c = 0; c < 2; ++c) {
      int ob = wid * 2048 + c * 1024 + lane * 16;
      int row = ob >> 6;
      int colB = ob & 63;
      gload_lds16(Arow + (size_t)row * 1024 + k0 + (colB >> 1), As + wid * 2048 + c * 1024);
      gload_lds16(Brow + (size_t)row * 1024 + k0 + (colB >> 1), Bs + wid * 2048 + c * 1024);
    }
    __syncthreads();
    bf16x8 a[4], b[4];
#pragma unroll
    for (int m = 0; m < 4; ++m)
      a[m] = *(const bf16x8*)(As + ((wr * 64 + m * 16 + r) * 64 + g * 16));
#pragma unroll
    for (int n = 0; n < 4; ++n)
      b[n] = *(const bf16x8*)(Bs + ((wc * 64 + n * 16 + r) * 64 + g * 16));
#pragma unroll
    for (int m = 0; m < 4; ++m)
#pragma unroll
      for (int n = 0; n < 4; ++n)
        acc[m][n] = __builtin_amdgcn_mfma_f32_16x16x32_bf16(a[m], b[n], acc[m][n], 0, 0, 0);
    __syncthreads();
  }
  const int colbase = bn * 128 + wc * 64;
  const int rowbase = bm * 128 + wr * 64;
  const int sec = colbase >> 10;  // 0=q 1=k 2=v, uniform per block
  // fold 1/sqrt(64) * log2(e) into Q so softmax can use exp2
  const float QSCALE = 0.125f * 1.44269504f;
#pragma unroll
  for (int m = 0; m < 4; ++m) {
#pragma unroll
    for (int n = 0; n < 4; ++n) {
#pragma unroll
      for (int reg = 0; reg < 4; ++reg) {
        int gm = rowbase + m * 16 + g * 4 + reg;
        int gn = colbase + n * 16 + r;
        float val = acc[m][n][reg] + bias[gn];
        int bb = gm >> 11, s = gm & 2047;
        int hc = gn & 1023;
        int h = hc >> 6, d = hc & 63;
        size_t oidx = (((size_t)(bb * 16 + h)) * 2048 + s) * 64 + d;
        if (sec == 0) qb[oidx] = f2bf(val * QSCALE);
        else if (sec == 1) kb[oidx] = f2bf(val);
        else vb[oidx] = f2bf(val);
      }
    }
  }
}

// ---------------- GEMM2: out = attn_out @ Wp + b (f32 out) ----------------
__global__ __launch_bounds__(256) void gemm_proj(const unsigned short* __restrict__ A,
                                                 const unsigned short* __restrict__ Bt,
                                                 const float* __restrict__ bias,
                                                 float* __restrict__ out) {
  __shared__ char smem[16384];
  char* As = smem;
  char* Bs = smem + 8192;
  const int tid = threadIdx.x;
  const int wid = tid >> 6, lane = tid & 63;
  const int g = lane >> 4, r = lane & 15;
  const int wr = wid >> 1, wc = wid & 1;
  const int bn = blockIdx.x, bm = blockIdx.y;
  f32x4 acc[4][4] = {};
  const unsigned short* Arow = A + (size_t)(bm * 128) * 1024;
  const unsigned short* Brow = Bt + (size_t)(bn * 128) * 1024;
  for (int k0 = 0; k0 < 1024; k0 += 32) {
#pragma unroll
    for (int c = 0; c < 2; ++c) {
      int ob = wid * 2048 + c * 1024 + lane * 16;
      int row = ob >> 6;
      int colB = ob & 63;
      gload_lds16(Arow + (size_t)row * 1024 + k0 + (colB >> 1), As + wid * 2048 + c * 1024);
      gload_lds16(Brow + (size_t)row * 1024 + k0 + (colB >> 1), Bs + wid * 2048 + c * 1024);
    }
    __syncthreads();
    bf16x8 a[4], b[4];
#pragma unroll
    for (int m = 0; m < 4; ++m)
      a[m] = *(const bf16x8*)(As + ((wr * 64 + m * 16 + r) * 64 + g * 16));
#pragma unroll
    for (int n = 0; n < 4; ++n)
      b[n] = *(const bf16x8*)(Bs + ((wc * 64 + n * 16 + r) * 64 + g * 16));
#pragma unroll
    for (int m = 0; m < 4; ++m)
#pragma unroll
      for (int n = 0; n < 4; ++n)
        acc[m][n] = __builtin_amdgcn_mfma_f32_16x16x32_bf16(a[m], b[n], acc[m][n], 0, 0, 0);
    __syncthreads();
  }
  const int colbase = bn * 128 + wc * 64;
  const int rowbase = bm * 128 + wr * 64;
#pragma unroll
  for (int m = 0; m < 4; ++m) {
#pragma unroll
    for (int n = 0; n < 4; ++n) {
#pragma unroll
      for (int reg = 0; reg < 4; ++reg) {
        int gm = rowbase + m * 16 + g * 4 + reg;
        int gn = colbase + n * 16 + r;
        out[(size_t)gm * 1024 + gn] = acc[m][n][reg] + bias[gn];
      }
    }
  }
}

// ---------------- flash attention, balanced + double-buffered ----------------
// q [B,H,S,D] (pre-scaled by 0.125*log2e), k [B,H,S,D], vt [B,H,D,S] -> aout [B*S,E] bf16
// Block bx handles q-tiles {bx, 15-bx} (constant 34 KV-tiles of work per block).
__global__ __launch_bounds__(256) void attn_kernel(const unsigned short* __restrict__ qb,
                                                   const unsigned short* __restrict__ kb,
                                                   const unsigned short* __restrict__ vtb,
                                                   unsigned short* __restrict__ aout) {
  __shared__ char smem[49152];
  // K bufs: smem + cur*8192 ; V bufs: smem + 16384 + cur*8192 ; P: smem + 32768 + wid*4096
  const int tid = threadIdx.x;
  const int wid = tid >> 6, lane = tid & 63;
  const int g = lane >> 4, r = lane & 15;
  const int bx = blockIdx.x, bh = blockIdx.y;
  char* Pl = smem + 32768 + wid * 4096;
  const unsigned short* qbase = qb + (size_t)bh * 2048 * 64;
  const unsigned short* kbh = kb + (size_t)bh * 2048 * 64;
  const unsigned short* vbh = vtb + (size_t)bh * 64 * 2048;

  auto stage = [&](int kt, int cbuf) {
    const int kv0 = kt * 64;
#pragma unroll
    for (int c = 0; c < 2; ++c) {
      int ob = wid * 2048 + c * 1024 + lane * 16;
      int row = ob >> 7;          // 128B per row
      int slot = (ob >> 4) & 7;
      int ss = slot ^ (row & 7);
      gload_lds16(kbh + ((size_t)(kv0 + row)) * 64 + ss * 8,
                  smem + cbuf * 8192 + wid * 2048 + c * 1024);
      gload_lds16(vbh + (size_t)row * 2048 + kv0 + ss * 8,
                  smem + 16384 + cbuf * 8192 + wid * 2048 + c * 1024);
    }
  };

#pragma unroll 1
  for (int pi = 0; pi < 2; ++pi) {
    const int qt = (pi == 0) ? bx : (15 - bx);
    const int qrow0 = qt * 128 + wid * 32;

    bf16x8 aq[2][2];
#pragma unroll
    for (int mf = 0; mf < 2; ++mf)
#pragma unroll
      for (int ks = 0; ks < 2; ++ks)
        aq[mf][ks] = *(const bf16x8*)(qbase + (size_t)(qrow0 + mf * 16 + r) * 64 + ks * 32 + g * 8);

    f32x4 o[2][4] = {};
    float mrow[2][4], lrow[2][4];
#pragma unroll
    for (int mf = 0; mf < 2; ++mf)
#pragma unroll
      for (int reg = 0; reg < 4; ++reg) { mrow[mf][reg] = -1e30f; lrow[mf][reg] = 0.f; }

    const int nkv = (qt + 1) * 2;
    int cur = 0;
    stage(0, 0);
    __syncthreads();

#pragma unroll 1
    for (int kt = 0; kt < nkv; ++kt) {
      const int kv0 = kt * 64;
      if (kt + 1 < nkv) stage(kt + 1, cur ^ 1);  // prefetch next tile (overlaps compute)
      char* Kt = smem + cur * 8192;
      char* Vt = smem + 16384 + cur * 8192;

      // scores: s[q][kv] = sum_d Q[q,d] K[kv,d]   (already in log2 domain)
      f32x4 s[2][4] = {};
#pragma unroll
      for (int ks = 0; ks < 2; ++ks) {
        bf16x8 bk[4];
#pragma unroll
        for (int nb = 0; nb < 4; ++nb) {
          int kv = nb * 16 + r;
          int slot = (ks * 4 + g) ^ (kv & 7);
          bk[nb] = *(const bf16x8*)(Kt + kv * 128 + slot * 16);
        }
#pragma unroll
        for (int mf = 0; mf < 2; ++mf)
#pragma unroll
          for (int nb = 0; nb < 4; ++nb)
            s[mf][nb] = __builtin_amdgcn_mfma_f32_16x16x32_bf16(aq[mf][ks], bk[nb], s[mf][nb], 0, 0, 0);
      }

      // causal mask (only the two diagonal-adjacent tiles need it)
      if (kt >= 2 * qt) {
#pragma unroll
        for (int mf = 0; mf < 2; ++mf)
#pragma unroll
          for (int nb = 0; nb < 4; ++nb)
#pragma unroll
            for (int reg = 0; reg < 4; ++reg) {
              int qg = qrow0 + mf * 16 + g * 4 + reg;
              int kg = kv0 + nb * 16 + r;
              s[mf][nb][reg] = (kg > qg) ? -1e30f : s[mf][nb][reg];
            }
      }

      // online softmax (base-2); row = g*4+reg lives in one 16-lane group
      float p[2][4][4];
#pragma unroll
      for (int mf = 0; mf < 2; ++mf)
#pragma unroll
        for (int reg = 0; reg < 4; ++reg) {
          float tm = s[mf][0][reg];
#pragma unroll
          for (int nb = 1; nb < 4; ++nb) tm = fmaxf(tm, s[mf][nb][reg]);
#pragma unroll
          for (int off = 1; off < 16; off <<= 1) tm = fmaxf(tm, __shfl_xor(tm, off));
          float mn = fmaxf(mrow[mf][reg], tm);
          float sc = exp2f(mrow[mf][reg] - mn);
          float rs = 0.f;
#pragma unroll
          for (int nb = 0; nb < 4; ++nb) {
            float pv = exp2f(s[mf][nb][reg] - mn);
            p[mf][nb][reg] = pv;
            rs += pv;
          }
#pragma unroll
          for (int off = 1; off < 16; off <<= 1) rs += __shfl_xor(rs, off);
          lrow[mf][reg] = lrow[mf][reg] * sc + rs;
          mrow[mf][reg] = mn;
#pragma unroll
          for (int db = 0; db < 4; ++db) o[mf][db][reg] *= sc;
        }

      // P -> per-wave LDS (swizzled), then PV
#pragma unroll
      for (int mf = 0; mf < 2; ++mf)
#pragma unroll
        for (int nb = 0; nb < 4; ++nb)
#pragma unroll
          for (int reg = 0; reg < 4; ++reg) {
            int row = mf * 16 + g * 4 + reg;
            int col = nb * 16 + r;
            int byte = (row * 128 + col * 2) ^ ((row & 7) << 4);
            *(unsigned short*)(Pl + byte) = f2bf(p[mf][nb][reg]);
          }
      asm volatile("s_waitcnt lgkmcnt(0)" ::: "memory");
#pragma unroll
      for (int ks = 0; ks < 2; ++ks) {
        bf16x8 pa[2], bv[4];
#pragma unroll
        for (int mf = 0; mf < 2; ++mf) {
          int row = mf * 16 + r;
          int slot = (ks * 4 + g) ^ (row & 7);
          pa[mf] = *(const bf16x8*)(Pl + row * 128 + slot * 16);
        }
#pragma unroll
        for (int db = 0; db < 4; ++db) {
          int d = db * 16 + r;
          int slot = (ks * 4 + g) ^ (d & 7);
          bv[db] = *(const bf16x8*)(Vt + d * 128 + slot * 16);
        }
#pragma unroll
        for (int mf = 0; mf < 2; ++mf)
#pragma unroll
          for (int db = 0; db < 4; ++db)
            o[mf][db] = __builtin_amdgcn_mfma_f32_16x16x32_bf16(pa[mf], bv[db], o[mf][db], 0, 0, 0);
      }
      __syncthreads();
      cur ^= 1;
    }

    // normalize and write merged-head output [B*S, E] bf16
    const int b_ = bh >> 4, h = bh & 15;
#pragma unroll
    for (int mf = 0; mf < 2; ++mf) {
#pragma unroll
      for (int reg = 0; reg < 4; ++reg) {
        float inv = 1.f / lrow[mf][reg];
        int rowg = b_ * 2048 + qrow0 + mf * 16 + g * 4 + reg;
#pragma unroll
        for (int db = 0; db < 4; ++db) {
          int colg = h * 64 + db * 16 + r;
          aout[(size_t)rowg * 1024 + colg] = f2bf(o[mf][db][reg] * inv);
        }
      }
    }
  }
}

extern "C" void kernel_launch(void* const* d_in, const int* in_sizes, int n_in,
                              void* d_out, int out_size, void* d_ws, size_t ws_size,
                              hipStream_t stream) {
  const float* hs = (const float*)d_in[0];      // [4,2048,1024]
  const float* w_attn = (const float*)d_in[1];  // [1024,3072]
  const float* b_attn = (const float*)d_in[2];  // [3072]
  const float* w_proj = (const float*)d_in[3];  // [1024,1024]
  const float* b_proj = (const float*)d_in[4];  // [1024]
  float* out = (float*)d_out;                   // [4,2048,1024] f32
  char* ws = (char*)d_ws;
  size_t off = 0;
  auto alloc = [&](size_t sz) {
    char* p = ws + off;
    off = (off + sz + 255) & ~(size_t)255;
    return p;
  };
  unsigned short* hs_bf = (unsigned short*)alloc((size_t)8192 * 1024 * 2);
  unsigned short* wattnT = (unsigned short*)alloc((size_t)3072 * 1024 * 2);
  unsigned short* wprojT = (unsigned short*)alloc((size_t)1024 * 1024 * 2);
  unsigned short* qb = (unsigned short*)alloc((size_t)8192 * 1024 * 2);
  unsigned short* kb = (unsigned short*)alloc((size_t)8192 * 1024 * 2);
  unsigned short* vb = (unsigned short*)alloc((size_t)8192 * 1024 * 2);
  unsigned short* vtb = (unsigned short*)alloc((size_t)8192 * 1024 * 2);
  unsigned short* aout = hs_bf;  // hs_bf dead after gemm_qkv; reuse

  cvt_f32_bf16<<<2048, 256, 0, stream>>>(hs, hs_bf, 8192 * 1024 / 4);
  transpose_cvt<<<dim3(48, 16), 256, 0, stream>>>(w_attn, wattnT, 1024, 3072);
  transpose_cvt<<<dim3(16, 16), 256, 0, stream>>>(w_proj, wprojT, 1024, 1024);
  gemm_qkv<<<dim3(24, 64), 256, 0, stream>>>(hs_bf, wattnT, b_attn, qb, kb, vb);
  transpose_b16<<<dim3(1, 32, 64), 256, 0, stream>>>(vb, vtb, 2048, 64);
  attn_kernel<<<dim3(8, 64), 256, 0, stream>>>(qb, kb, vtb, aout);
  gemm_proj<<<dim3(8, 64), 256, 0, stream>>>(aout, wprojT, b_proj, out);
}

// Round 3
// 213.856 us; speedup vs baseline: 1.5773x; 1.2004x over previous
//
#include <hip/hip_runtime.h>
#include <stdint.h>

typedef short bf16x8 __attribute__((ext_vector_type(8)));
typedef float f32x4 __attribute__((ext_vector_type(4)));
typedef unsigned short u16x4 __attribute__((ext_vector_type(4)));

__device__ __forceinline__ unsigned short f2bf(float f) {
  unsigned int u = __builtin_bit_cast(unsigned int, f);
  u += 0x7fffu + ((u >> 16) & 1u);
  return (unsigned short)(u >> 16);
}

__device__ __forceinline__ void gload_lds16(const void* g, void* l) {
  __builtin_amdgcn_global_load_lds(
      (const __attribute__((address_space(1))) unsigned int*)g,
      (__attribute__((address_space(3))) unsigned int*)l, 16, 0, 0);
}

// ---------------- elementwise f32 -> bf16 ----------------
__global__ __launch_bounds__(256) void cvt_f32_bf16(const float* __restrict__ in,
                                                    unsigned short* __restrict__ out, int n4) {
  int i = blockIdx.x * blockDim.x + threadIdx.x;
  int stride = gridDim.x * blockDim.x;
  for (; i < n4; i += stride) {
    float4 v = ((const float4*)in)[i];
    ushort4 o;
    o.x = f2bf(v.x); o.y = f2bf(v.y); o.z = f2bf(v.z); o.w = f2bf(v.w);
    ((ushort4*)out)[i] = o;
  }
}

// ---------------- transpose + convert f32[R][C] -> bf16[C][R] ----------------
__global__ __launch_bounds__(256) void transpose_cvt(const float* __restrict__ in,
                                                     unsigned short* __restrict__ out,
                                                     int R, int C) {
  __shared__ unsigned short t[64][65];
  int c0 = blockIdx.x * 64, r0 = blockIdx.y * 64;
  int tid = threadIdx.x;
#pragma unroll
  for (int i = 0; i < 16; ++i) {
    int idx = tid + i * 256;
    int rr = idx >> 6, cc = idx & 63;
    t[rr][cc] = f2bf(in[(size_t)(r0 + rr) * C + c0 + cc]);
  }
  __syncthreads();
#pragma unroll
  for (int i = 0; i < 16; ++i) {
    int idx = tid + i * 256;
    int rr = idx >> 6, cc = idx & 63;
    out[(size_t)(c0 + rr) * R + r0 + cc] = t[cc][rr];
  }
}

// ---------------- batched transpose bf16[z][R][C] -> bf16[z][C][R] ----------------
__global__ __launch_bounds__(256) void transpose_b16(const unsigned short* __restrict__ in,
                                                     unsigned short* __restrict__ out,
                                                     int R, int C) {
  __shared__ unsigned short t[64][65];
  const unsigned short* ip = in + (size_t)blockIdx.z * R * C;
  unsigned short* op = out + (size_t)blockIdx.z * R * C;
  int c0 = blockIdx.x * 64, r0 = blockIdx.y * 64;
  int tid = threadIdx.x;
#pragma unroll
  for (int i = 0; i < 16; ++i) {
    int idx = tid + i * 256;
    int rr = idx >> 6, cc = idx & 63;
    t[rr][cc] = ip[(size_t)(r0 + rr) * C + c0 + cc];
  }
  __syncthreads();
#pragma unroll
  for (int i = 0; i < 16; ++i) {
    int idx = tid + i * 256;
    int rr = idx >> 6, cc = idx & 63;
    op[(size_t)(c0 + rr) * R + r0 + cc] = t[cc][rr];
  }
}

// ---------------- GEMM1: qkv = hs @ W + b, scatter to q/k/v [B,H,S,D] bf16 ----------------
__global__ __launch_bounds__(256) void gemm_qkv(const unsigned short* __restrict__ A,
                                                const unsigned short* __restrict__ Bt,
                                                const float* __restrict__ bias,
                                                unsigned short* __restrict__ qb,
                                                unsigned short* __restrict__ kb,
                                                unsigned short* __restrict__ vb) {
  __shared__ char smem[16384];
  char* As = smem;
  char* Bs = smem + 8192;
  const int tid = threadIdx.x;
  const int wid = tid >> 6, lane = tid & 63;
  const int g = lane >> 4, r = lane & 15;
  const int wr = wid >> 1, wc = wid & 1;
  const int bn = blockIdx.x, bm = blockIdx.y;
  f32x4 acc[4][4] = {};
  const unsigned short* Arow = A + (size_t)(bm * 128) * 1024;
  const unsigned short* Brow = Bt + (size_t)(bn * 128) * 1024;
  for (int k0 = 0; k0 < 1024; k0 += 32) {
#pragma unroll
    for (int c = 0; c < 2; ++c) {
      int ob = wid * 2048 + c * 1024 + lane * 16;
      int row = ob >> 6;
      int colB = ob & 63;
      gload_lds16(Arow + (size_t)row * 1024 + k0 + (colB >> 1), As + wid * 2048 + c * 1024);
      gload_lds16(Brow + (size_t)row * 1024 + k0 + (colB >> 1), Bs + wid * 2048 + c * 1024);
    }
    __syncthreads();
    bf16x8 a[4], b[4];
#pragma unroll
    for (int m = 0; m < 4; ++m)
      a[m] = *(const bf16x8*)(As + ((wr * 64 + m * 16 + r) * 64 + g * 16));
#pragma unroll
    for (int n = 0; n < 4; ++n)
      b[n] = *(const bf16x8*)(Bs + ((wc * 64 + n * 16 + r) * 64 + g * 16));
#pragma unroll
    for (int m = 0; m < 4; ++m)
#pragma unroll
      for (int n = 0; n < 4; ++n)
        acc[m][n] = __builtin_amdgcn_mfma_f32_16x16x32_bf16(a[m], b[n], acc[m][n], 0, 0, 0);
    __syncthreads();
  }
  const int colbase = bn * 128 + wc * 64;
  const int rowbase = bm * 128 + wr * 64;
  const int sec = colbase >> 10;  // 0=q 1=k 2=v, uniform per block
  // fold 1/sqrt(64) * log2(e) into Q so softmax can use exp2
  const float QSCALE = 0.125f * 1.44269504f;
#pragma unroll
  for (int m = 0; m < 4; ++m) {
#pragma unroll
    for (int n = 0; n < 4; ++n) {
#pragma unroll
      for (int reg = 0; reg < 4; ++reg) {
        int gm = rowbase + m * 16 + g * 4 + reg;
        int gn = colbase + n * 16 + r;
        float val = acc[m][n][reg] + bias[gn];
        int bb = gm >> 11, s = gm & 2047;
        int hc = gn & 1023;
        int h = hc >> 6, d = hc & 63;
        size_t oidx = (((size_t)(bb * 16 + h)) * 2048 + s) * 64 + d;
        if (sec == 0) qb[oidx] = f2bf(val * QSCALE);
        else if (sec == 1) kb[oidx] = f2bf(val);
        else vb[oidx] = f2bf(val);
      }
    }
  }
}

// ---------------- GEMM2: out = attn_out @ Wp + b (f32 out) ----------------
__global__ __launch_bounds__(256) void gemm_proj(const unsigned short* __restrict__ A,
                                                 const unsigned short* __restrict__ Bt,
                                                 const float* __restrict__ bias,
                                                 float* __restrict__ out) {
  __shared__ char smem[16384];
  char* As = smem;
  char* Bs = smem + 8192;
  const int tid = threadIdx.x;
  const int wid = tid >> 6, lane = tid & 63;
  const int g = lane >> 4, r = lane & 15;
  const int wr = wid >> 1, wc = wid & 1;
  const int bn = blockIdx.x, bm = blockIdx.y;
  f32x4 acc[4][4] = {};
  const unsigned short* Arow = A + (size_t)(bm * 128) * 1024;
  const unsigned short* Brow = Bt + (size_t)(bn * 128) * 1024;
  for (int k0 = 0; k0 < 1024; k0 += 32) {
#pragma unroll
    for (int c = 0; c < 2; ++c) {
      int ob = wid * 2048 + c * 1024 + lane * 16;
      int row = ob >> 6;
      int colB = ob & 63;
      gload_lds16(Arow + (size_t)row * 1024 + k0 + (colB >> 1), As + wid * 2048 + c * 1024);
      gload_lds16(Brow + (size_t)row * 1024 + k0 + (colB >> 1), Bs + wid * 2048 + c * 1024);
    }
    __syncthreads();
    bf16x8 a[4], b[4];
#pragma unroll
    for (int m = 0; m < 4; ++m)
      a[m] = *(const bf16x8*)(As + ((wr * 64 + m * 16 + r) * 64 + g * 16));
#pragma unroll
    for (int n = 0; n < 4; ++n)
      b[n] = *(const bf16x8*)(Bs + ((wc * 64 + n * 16 + r) * 64 + g * 16));
#pragma unroll
    for (int m = 0; m < 4; ++m)
#pragma unroll
      for (int n = 0; n < 4; ++n)
        acc[m][n] = __builtin_amdgcn_mfma_f32_16x16x32_bf16(a[m], b[n], acc[m][n], 0, 0, 0);
    __syncthreads();
  }
  const int colbase = bn * 128 + wc * 64;
  const int rowbase = bm * 128 + wr * 64;
#pragma unroll
  for (int m = 0; m < 4; ++m) {
#pragma unroll
    for (int n = 0; n < 4; ++n) {
#pragma unroll
      for (int reg = 0; reg < 4; ++reg) {
        int gm = rowbase + m * 16 + g * 4 + reg;
        int gn = colbase + n * 16 + r;
        out[(size_t)gm * 1024 + gn] = acc[m][n][reg] + bias[gn];
      }
    }
  }
}

// ---------------- flash attention: swapped QK^T + defer-max ----------------
// q [B,H,S,D] (pre-scaled by 0.125*log2e), k [B,H,S,D], vt [B,H,D,S] -> aout [B*S,E] bf16
// Block bx handles q-tiles {bx, 15-bx} (constant 34 KV-tiles per block).
__global__ __launch_bounds__(256) void attn_kernel(const unsigned short* __restrict__ qb,
                                                   const unsigned short* __restrict__ kb,
                                                   const unsigned short* __restrict__ vtb,
                                                   unsigned short* __restrict__ aout) {
  __shared__ char smem[49152];
  // K bufs: smem + cur*8192 ; V bufs: smem + 16384 + cur*8192 ; P: smem + 32768 + wid*4096
  const int tid = threadIdx.x;
  const int wid = tid >> 6, lane = tid & 63;
  const int g = lane >> 4, r = lane & 15;
  const int bx = blockIdx.x, bh = blockIdx.y;
  char* Pl = smem + 32768 + wid * 4096;
  const unsigned short* qbase = qb + (size_t)bh * 2048 * 64;
  const unsigned short* kbh = kb + (size_t)bh * 2048 * 64;
  const unsigned short* vbh = vtb + (size_t)bh * 64 * 2048;

  auto stage = [&](int kt, int cbuf) {
    const int kv0 = kt * 64;
#pragma unroll
    for (int c = 0; c < 2; ++c) {
      int ob = wid * 2048 + c * 1024 + lane * 16;
      int row = ob >> 7;          // 128B per row
      int slot = (ob >> 4) & 7;
      int ss = slot ^ (row & 7);
      gload_lds16(kbh + ((size_t)(kv0 + row)) * 64 + ss * 8,
                  smem + cbuf * 8192 + wid * 2048 + c * 1024);
      gload_lds16(vbh + (size_t)row * 2048 + kv0 + ss * 8,
                  smem + 16384 + cbuf * 8192 + wid * 2048 + c * 1024);
    }
  };

#pragma unroll 1
  for (int pi = 0; pi < 2; ++pi) {
    const int qt = (pi == 0) ? bx : (15 - bx);
    const int qrow0 = qt * 128 + wid * 32;

    bf16x8 aq[2][2];
#pragma unroll
    for (int qf = 0; qf < 2; ++qf)
#pragma unroll
      for (int ks = 0; ks < 2; ++ks)
        aq[qf][ks] = *(const bf16x8*)(qbase + (size_t)(qrow0 + qf * 16 + r) * 64 + ks * 32 + g * 8);

    f32x4 o[2][4] = {};
    float mrow[2] = {-1e30f, -1e30f};
    float lrow[2] = {0.f, 0.f};

    const int nkv = (qt + 1) * 2;
    int cur = 0;
    stage(0, 0);
    __syncthreads();

#pragma unroll 1
    for (int kt = 0; kt < nkv; ++kt) {
      const int kv0 = kt * 64;
      if (kt + 1 < nkv) stage(kt + 1, cur ^ 1);  // prefetch next tile (overlaps compute)
      char* Kt = smem + cur * 8192;
      char* Vt = smem + 16384 + cur * 8192;

      // swapped scores: sw[kf][qf] = D[kv_local][q_local] = K·Q^T
      // lane holds q = qf*16 + r, kv = kf*16 + g*4 + reg  -> row data is lane-local
      f32x4 sw[4][2] = {};
#pragma unroll
      for (int ks = 0; ks < 2; ++ks) {
        bf16x8 bk[4];
#pragma unroll
        for (int kf = 0; kf < 4; ++kf) {
          int kv = kf * 16 + r;
          int slot = (ks * 4 + g) ^ (kv & 7);
          bk[kf] = *(const bf16x8*)(Kt + kv * 128 + slot * 16);
        }
        __builtin_amdgcn_s_setprio(1);
#pragma unroll
        for (int kf = 0; kf < 4; ++kf)
#pragma unroll
          for (int qf = 0; qf < 2; ++qf)
            sw[kf][qf] = __builtin_amdgcn_mfma_f32_16x16x32_bf16(bk[kf], aq[qf][ks], sw[kf][qf], 0, 0, 0);
        __builtin_amdgcn_s_setprio(0);
      }

      // causal mask (only the two diagonal-adjacent tiles need it)
      if (kt >= 2 * qt) {
#pragma unroll
        for (int kf = 0; kf < 4; ++kf)
#pragma unroll
          for (int qf = 0; qf < 2; ++qf)
#pragma unroll
            for (int reg = 0; reg < 4; ++reg) {
              int qg = qrow0 + qf * 16 + r;
              int kg = kv0 + kf * 16 + g * 4 + reg;
              sw[kf][qf][reg] = (kg > qg) ? -1e30f : sw[kf][qf][reg];
            }
      }

      // tile max per q-row: 15 register fmax + 2 shfl (over the 4 lane-groups)
      float tm[2];
#pragma unroll
      for (int qf = 0; qf < 2; ++qf) {
        float t = sw[0][qf][0];
#pragma unroll
        for (int kf = 0; kf < 4; ++kf)
#pragma unroll
          for (int reg = 0; reg < 4; ++reg) t = fmaxf(t, sw[kf][qf][reg]);
        t = fmaxf(t, __shfl_xor(t, 16));
        t = fmaxf(t, __shfl_xor(t, 32));
        tm[qf] = t;
      }

      // defer-max: skip O-rescale when growth small (P bounded by 2^8)
      bool noresc = ((tm[0] - mrow[0]) <= 8.0f) && ((tm[1] - mrow[1]) <= 8.0f);
      if (!__all(noresc)) {
        float scv[2];
#pragma unroll
        for (int qf = 0; qf < 2; ++qf) {
          float mn = fmaxf(mrow[qf], tm[qf]);
          scv[qf] = exp2f(mrow[qf] - mn);
          lrow[qf] *= scv[qf];
          mrow[qf] = mn;
        }
#pragma unroll
        for (int mf = 0; mf < 2; ++mf)
#pragma unroll
          for (int reg = 0; reg < 4; ++reg) {
            float sb = __shfl(scv[mf], ((lane >> 4) << 2) + reg);
#pragma unroll
            for (int db = 0; db < 4; ++db) o[mf][db][reg] *= sb;
          }
      }

      // P = exp2(s - m), row-sum in registers + 2 shfl
      float p[4][2][4];
      float rs[2] = {0.f, 0.f};
#pragma unroll
      for (int kf = 0; kf < 4; ++kf)
#pragma unroll
        for (int qf = 0; qf < 2; ++qf)
#pragma unroll
          for (int reg = 0; reg < 4; ++reg) {
            float pv = exp2f(sw[kf][qf][reg] - mrow[qf]);
            p[kf][qf][reg] = pv;
            rs[qf] += pv;
          }
#pragma unroll
      for (int qf = 0; qf < 2; ++qf) {
        float t = rs[qf];
        t += __shfl_xor(t, 16);
        t += __shfl_xor(t, 32);
        lrow[qf] += t;
      }

      // P -> per-wave LDS: 8 packed 8-byte writes (kv-consecutive within a row)
#pragma unroll
      for (int qf = 0; qf < 2; ++qf) {
        int row = qf * 16 + r;
        int rbase = row * 128;
        int swz = (row & 7) << 4;
#pragma unroll
        for (int kf = 0; kf < 4; ++kf) {
          int byte = (rbase + kf * 32 + g * 8) ^ swz;
          u16x4 w;
          w.x = f2bf(p[kf][qf][0]);
          w.y = f2bf(p[kf][qf][1]);
          w.z = f2bf(p[kf][qf][2]);
          w.w = f2bf(p[kf][qf][3]);
          *(u16x4*)(Pl + byte) = w;
        }
      }
      asm volatile("s_waitcnt lgkmcnt(0)" ::: "memory");

      // PV: o[q][d] += P[q][kv] Vt[d][kv]
#pragma unroll
      for (int ks = 0; ks < 2; ++ks) {
        bf16x8 pa[2], bv[4];
#pragma unroll
        for (int mf = 0; mf < 2; ++mf) {
          int row = mf * 16 + r;
          int slot = (ks * 4 + g) ^ (row & 7);
          pa[mf] = *(const bf16x8*)(Pl + row * 128 + slot * 16);
        }
#pragma unroll
        for (int db = 0; db < 4; ++db) {
          int d = db * 16 + r;
          int slot = (ks * 4 + g) ^ (d & 7);
          bv[db] = *(const bf16x8*)(Vt + d * 128 + slot * 16);
        }
        __builtin_amdgcn_s_setprio(1);
#pragma unroll
        for (int mf = 0; mf < 2; ++mf)
#pragma unroll
          for (int db = 0; db < 4; ++db)
            o[mf][db] = __builtin_amdgcn_mfma_f32_16x16x32_bf16(pa[mf], bv[db], o[mf][db], 0, 0, 0);
        __builtin_amdgcn_s_setprio(0);
      }
      __syncthreads();
      cur ^= 1;
    }

    // normalize (broadcast 1/l to o's row owners) and write [B*S, E] bf16
    const int b_ = bh >> 4, h = bh & 15;
    float invq[2] = {1.f / lrow[0], 1.f / lrow[1]};
#pragma unroll
    for (int mf = 0; mf < 2; ++mf) {
#pragma unroll
      for (int reg = 0; reg < 4; ++reg) {
        float inv = __shfl(invq[mf], ((lane >> 4) << 2) + reg);
        int rowg = b_ * 2048 + qrow0 + mf * 16 + g * 4 + reg;
#pragma unroll
        for (int db = 0; db < 4; ++db) {
          int colg = h * 64 + db * 16 + r;
          aout[(size_t)rowg * 1024 + colg] = f2bf(o[mf][db][reg] * inv);
        }
      }
    }
  }
}

extern "C" void kernel_launch(void* const* d_in, const int* in_sizes, int n_in,
                              void* d_out, int out_size, void* d_ws, size_t ws_size,
                              hipStream_t stream) {
  const float* hs = (const float*)d_in[0];      // [4,2048,1024]
  const float* w_attn = (const float*)d_in[1];  // [1024,3072]
  const float* b_attn = (const float*)d_in[2];  // [3072]
  const float* w_proj = (const float*)d_in[3];  // [1024,1024]
  const float* b_proj = (const float*)d_in[4];  // [1024]
  float* out = (float*)d_out;                   // [4,2048,1024] f32
  char* ws = (char*)d_ws;
  size_t off = 0;
  auto alloc = [&](size_t sz) {
    char* p = ws + off;
    off = (off + sz + 255) & ~(size_t)255;
    return p;
  };
  unsigned short* hs_bf = (unsigned short*)alloc((size_t)8192 * 1024 * 2);
  unsigned short* wattnT = (unsigned short*)alloc((size_t)3072 * 1024 * 2);
  unsigned short* wprojT = (unsigned short*)alloc((size_t)1024 * 1024 * 2);
  unsigned short* qb = (unsigned short*)alloc((size_t)8192 * 1024 * 2);
  unsigned short* kb = (unsigned short*)alloc((size_t)8192 * 1024 * 2);
  unsigned short* vb = (unsigned short*)alloc((size_t)8192 * 1024 * 2);
  unsigned short* vtb = (unsigned short*)alloc((size_t)8192 * 1024 * 2);
  unsigned short* aout = hs_bf;  // hs_bf dead after gemm_qkv; reuse

  cvt_f32_bf16<<<2048, 256, 0, stream>>>(hs, hs_bf, 8192 * 1024 / 4);
  transpose_cvt<<<dim3(48, 16), 256, 0, stream>>>(w_attn, wattnT, 1024, 3072);
  transpose_cvt<<<dim3(16, 16), 256, 0, stream>>>(w_proj, wprojT, 1024, 1024);
  gemm_qkv<<<dim3(24, 64), 256, 0, stream>>>(hs_bf, wattnT, b_attn, qb, kb, vb);
  transpose_b16<<<dim3(1, 32, 64), 256, 0, stream>>>(vb, vtb, 2048, 64);
  attn_kernel<<<dim3(8, 64), 256, 0, stream>>>(qb, kb, vtb, aout);
  gemm_proj<<<dim3(8, 64), 256, 0, stream>>>(aout, wprojT, b_proj, out);
}

// Round 4
// 206.168 us; speedup vs baseline: 1.6361x; 1.0373x over previous
//
#include <hip/hip_runtime.h>
#include <stdint.h>

typedef short bf16x8 __attribute__((ext_vector_type(8)));
typedef float f32x4 __attribute__((ext_vector_type(4)));

__device__ __forceinline__ unsigned short f2bf(float f) {
  unsigned int u = __builtin_bit_cast(unsigned int, f);
  u += 0x7fffu + ((u >> 16) & 1u);
  return (unsigned short)(u >> 16);
}

__device__ __forceinline__ void gload_lds16(const void* g, void* l) {
  __builtin_amdgcn_global_load_lds(
      (const __attribute__((address_space(1))) unsigned int*)g,
      (__attribute__((address_space(3))) unsigned int*)l, 16, 0, 0);
}

// ---------------- elementwise f32 -> bf16 ----------------
__global__ __launch_bounds__(256) void cvt_f32_bf16(const float* __restrict__ in,
                                                    unsigned short* __restrict__ out, int n4) {
  int i = blockIdx.x * blockDim.x + threadIdx.x;
  int stride = gridDim.x * blockDim.x;
  for (; i < n4; i += stride) {
    float4 v = ((const float4*)in)[i];
    ushort4 o;
    o.x = f2bf(v.x); o.y = f2bf(v.y); o.z = f2bf(v.z); o.w = f2bf(v.w);
    ((ushort4*)out)[i] = o;
  }
}

// ---------------- transpose + convert f32[R][C] -> bf16[C][R] ----------------
__global__ __launch_bounds__(256) void transpose_cvt(const float* __restrict__ in,
                                                     unsigned short* __restrict__ out,
                                                     int R, int C) {
  __shared__ unsigned short t[64][65];
  int c0 = blockIdx.x * 64, r0 = blockIdx.y * 64;
  int tid = threadIdx.x;
#pragma unroll
  for (int i = 0; i < 16; ++i) {
    int idx = tid + i * 256;
    int rr = idx >> 6, cc = idx & 63;
    t[rr][cc] = f2bf(in[(size_t)(r0 + rr) * C + c0 + cc]);
  }
  __syncthreads();
#pragma unroll
  for (int i = 0; i < 16; ++i) {
    int idx = tid + i * 256;
    int rr = idx >> 6, cc = idx & 63;
    out[(size_t)(c0 + rr) * R + r0 + cc] = t[cc][rr];
  }
}

// ---------------- batched transpose bf16[z][R][C] -> bf16[z][C][R] ----------------
__global__ __launch_bounds__(256) void transpose_b16(const unsigned short* __restrict__ in,
                                                     unsigned short* __restrict__ out,
                                                     int R, int C) {
  __shared__ unsigned short t[64][65];
  const unsigned short* ip = in + (size_t)blockIdx.z * R * C;
  unsigned short* op = out + (size_t)blockIdx.z * R * C;
  int c0 = blockIdx.x * 64, r0 = blockIdx.y * 64;
  int tid = threadIdx.x;
#pragma unroll
  for (int i = 0; i < 16; ++i) {
    int idx = tid + i * 256;
    int rr = idx >> 6, cc = idx & 63;
    t[rr][cc] = ip[(size_t)(r0 + rr) * C + c0 + cc];
  }
  __syncthreads();
#pragma unroll
  for (int i = 0; i < 16; ++i) {
    int idx = tid + i * 256;
    int rr = idx >> 6, cc = idx & 63;
    op[(size_t)(c0 + rr) * R + r0 + cc] = t[cc][rr];
  }
}

// =========== 256-wide 8-wave double-buffered K-loop (BK=64), swizzled LDS ===========
// A [M rows][ldA] bf16 row-major; Bt [N rows][ldB] bf16 (output-col major, K contiguous).
// Block tile: 256 (M) x BN. Waves: WN along N, 8/WN along M; per-wave 64 cols, 16*MI rows.
// LDS: A dbuf 2x32KB @0; B dbuf 2x(BN*128) @65536. XOR-swizzle ((row&7)<<4) applied on
// ds_read addresses; staged via linear-dest global_load_lds with pre-swizzled source col.
template <int BN, int WN>
__device__ __forceinline__ void kloop256(const unsigned short* __restrict__ Ab,
                                         const unsigned short* __restrict__ Bb,
                                         char* smem, f32x4 (*acc)[4], int ldA, int ldB) {
  constexpr int MI = 2 * WN;          // m-fragments per wave
  constexpr int NC = (256 + BN) / 64; // gload16 calls per K-tile per thread
  constexpr int BUFB = BN * 128;      // bytes per B buffer
  const int tid = threadIdx.x;
  const int lane = tid & 63, wid = tid >> 6;
  const int g = lane >> 4, r = lane & 15;
  const int wr = wid / WN, wc = wid % WN;

  // staging: call c -> LDS linear dest; global source pre-swizzled within the 128B row
  const int srow = (tid >> 3) & 63;  // row within 64-row group
  const int scol = (((tid << 4) & 127) ^ ((srow & 7) << 4)) >> 1;
  const unsigned short* gp[NC];
  int dst[NC];
#pragma unroll
  for (int c = 0; c < NC; ++c) {
    if (c < 4) {
      gp[c] = Ab + (size_t)(c * 64 + srow) * ldA + scol;
      dst[c] = c * 8192 + tid * 16;
    } else {
      gp[c] = Bb + (size_t)((c - 4) * 64 + srow) * ldB + scol;
      dst[c] = 65536 + (c - 4) * 8192 + tid * 16;
    }
  }

  // fragment read offsets (ks=0; ks=1 -> ^64)
  int aoff[MI], boff[4];
#pragma unroll
  for (int mi = 0; mi < MI; ++mi) {
    int row = wr * (16 * MI) + mi * 16 + r;
    aoff[mi] = row * 128 + ((g * 16) ^ ((row & 7) << 4));
  }
#pragma unroll
  for (int ni = 0; ni < 4; ++ni) {
    int row = wc * 64 + ni * 16 + r;
    boff[ni] = 65536 + row * 128 + ((g * 16) ^ ((row & 7) << 4));
  }

  int cur = 0;
  // prologue: stage K-tile 0 into buffer 0
#pragma unroll
  for (int c = 0; c < NC; ++c) {
    gload_lds16(gp[c], smem + dst[c]);
    gp[c] += 64;
  }
  __syncthreads();

  for (int kt = 0; kt < 16; ++kt) {
    const int abase = cur * 32768, bbase = cur * BUFB;
    const int nbA = (cur ^ 1) * 32768, nbB = (cur ^ 1) * BUFB;
    const bool pre = (kt < 15);
    bf16x8 bfr[4];
#pragma unroll
    for (int p = 0; p < 4; ++p) {
      if (pre) {
#pragma unroll
        for (int c = 2 * p; c < 2 * p + 2; ++c)
          if (c < NC) {
            gload_lds16(gp[c], smem + dst[c] + (c < 4 ? nbA : nbB));
            gp[c] += 64;
          }
      }
      const int ks = p >> 1, mh = p & 1;
      const int kx = ks ? 64 : 0;
      if (mh == 0) {
#pragma unroll
        for (int ni = 0; ni < 4; ++ni)
          bfr[ni] = *(const bf16x8*)(smem + ((boff[ni] ^ kx) + bbase));
      }
      bf16x8 afr[MI / 2];
#pragma unroll
      for (int i = 0; i < MI / 2; ++i)
        afr[i] = *(const bf16x8*)(smem + ((aoff[mh * (MI / 2) + i] ^ kx) + abase));
      __builtin_amdgcn_s_setprio(1);
#pragma unroll
      for (int i = 0; i < MI / 2; ++i)
#pragma unroll
        for (int ni = 0; ni < 4; ++ni)
          acc[mh * (MI / 2) + i][ni] =
              __builtin_amdgcn_mfma_f32_16x16x32_bf16(afr[i], bfr[ni], acc[mh * (MI / 2) + i][ni], 0, 0, 0);
      __builtin_amdgcn_s_setprio(0);
    }
    __syncthreads();
    cur ^= 1;
  }
}

// ---------------- GEMM1: qkv = hs @ W + b, scatter to q/k/v [B,H,S,D] bf16 ----------------
__global__ __launch_bounds__(512, 2) void gemm_qkv(const unsigned short* __restrict__ A,
                                                   const unsigned short* __restrict__ Bt,
                                                   const float* __restrict__ bias,
                                                   unsigned short* __restrict__ qb,
                                                   unsigned short* __restrict__ kb,
                                                   unsigned short* __restrict__ vb) {
  __shared__ __align__(16) char smem[131072];
  const int tid = threadIdx.x;
  const int lane = tid & 63, wid = tid >> 6;
  const int g = lane >> 4, r = lane & 15;
  const int wr = wid >> 2, wc = wid & 3;
  const int bn = blockIdx.x, bm = blockIdx.y;
  f32x4 acc[8][4] = {};
  kloop256<256, 4>(A + (size_t)(bm * 256) * 1024, Bt + (size_t)(bn * 256) * 1024, smem, acc, 1024, 1024);

  const int colbase = bn * 256 + wc * 64;
  const int rowbase = bm * 256 + wr * 128;
  const int sec = colbase >> 10;  // 0=q 1=k 2=v, uniform per wave
  const float QSCALE = 0.125f * 1.44269504f;  // fold 1/sqrt(64)*log2(e) into Q
#pragma unroll
  for (int m = 0; m < 8; ++m) {
#pragma unroll
    for (int n = 0; n < 4; ++n) {
#pragma unroll
      for (int reg = 0; reg < 4; ++reg) {
        int gm = rowbase + m * 16 + g * 4 + reg;
        int gn = colbase + n * 16 + r;
        float val = acc[m][n][reg] + bias[gn];
        int bb = gm >> 11, s = gm & 2047;
        int hc = gn & 1023;
        int h = hc >> 6, d = hc & 63;
        size_t oidx = (((size_t)(bb * 16 + h)) * 2048 + s) * 64 + d;
        if (sec == 0) qb[oidx] = f2bf(val * QSCALE);
        else if (sec == 1) kb[oidx] = f2bf(val);
        else vb[oidx] = f2bf(val);
      }
    }
  }
}

// ---------------- GEMM2: out = attn_out @ Wp + b (f32 out) ----------------
__global__ __launch_bounds__(512, 2) void gemm_proj(const unsigned short* __restrict__ A,
                                                    const unsigned short* __restrict__ Bt,
                                                    const float* __restrict__ bias,
                                                    float* __restrict__ out) {
  __shared__ __align__(16) char smem[98304];
  const int tid = threadIdx.x;
  const int lane = tid & 63, wid = tid >> 6;
  const int g = lane >> 4, r = lane & 15;
  const int wr = wid >> 1, wc = wid & 1;
  const int bn = blockIdx.x, bm = blockIdx.y;
  f32x4 acc[4][4] = {};
  kloop256<128, 2>(A + (size_t)(bm * 256) * 1024, Bt + (size_t)(bn * 128) * 1024, smem, acc, 1024, 1024);

  const int colbase = bn * 128 + wc * 64;
  const int rowbase = bm * 256 + wr * 64;
#pragma unroll
  for (int m = 0; m < 4; ++m) {
#pragma unroll
    for (int n = 0; n < 4; ++n) {
#pragma unroll
      for (int reg = 0; reg < 4; ++reg) {
        int gm = rowbase + m * 16 + g * 4 + reg;
        int gn = colbase + n * 16 + r;
        out[(size_t)gm * 1024 + gn] = acc[m][n][reg] + bias[gn];
      }
    }
  }
}

// ---------------- flash attention: swapped QK^T + defer-max ----------------
// q [B,H,S,D] (pre-scaled by 0.125*log2e), k [B,H,S,D], vt [B,H,D,S] -> aout [B*S,E] bf16
// Block bx handles q-tiles {bx, 15-bx} (constant 34 KV-tiles per block).
__global__ __launch_bounds__(256) void attn_kernel(const unsigned short* __restrict__ qb,
                                                   const unsigned short* __restrict__ kb,
                                                   const unsigned short* __restrict__ vtb,
                                                   unsigned short* __restrict__ aout) {
  __shared__ char smem[49152];
  const int tid = threadIdx.x;
  const int wid = tid >> 6, lane = tid & 63;
  const int g = lane >> 4, r = lane & 15;
  const int bx = blockIdx.x, bh = blockIdx.y;
  char* Pl = smem + 32768 + wid * 4096;
  const unsigned short* qbase = qb + (size_t)bh * 2048 * 64;
  const unsigned short* kbh = kb + (size_t)bh * 2048 * 64;
  const unsigned short* vbh = vtb + (size_t)bh * 64 * 2048;

  auto stage = [&](int kt, int cbuf) {
    const int kv0 = kt * 64;
#pragma unroll
    for (int c = 0; c < 2; ++c) {
      int ob = wid * 2048 + c * 1024 + lane * 16;
      int row = ob >> 7;          // 128B per row
      int slot = (ob >> 4) & 7;
      int ss = slot ^ (row & 7);
      gload_lds16(kbh + ((size_t)(kv0 + row)) * 64 + ss * 8,
                  smem + cbuf * 8192 + wid * 2048 + c * 1024);
      gload_lds16(vbh + (size_t)row * 2048 + kv0 + ss * 8,
                  smem + 16384 + cbuf * 8192 + wid * 2048 + c * 1024);
    }
  };

#pragma unroll 1
  for (int pi = 0; pi < 2; ++pi) {
    const int qt = (pi == 0) ? bx : (15 - bx);
    const int qrow0 = qt * 128 + wid * 32;

    bf16x8 aq[2][2];
#pragma unroll
    for (int qf = 0; qf < 2; ++qf)
#pragma unroll
      for (int ks = 0; ks < 2; ++ks)
        aq[qf][ks] = *(const bf16x8*)(qbase + (size_t)(qrow0 + qf * 16 + r) * 64 + ks * 32 + g * 8);

    f32x4 o[2][4] = {};
    float mrow[2] = {-1e30f, -1e30f};
    float lrow[2] = {0.f, 0.f};

    const int nkv = (qt + 1) * 2;
    int cur = 0;
    stage(0, 0);
    __syncthreads();

#pragma unroll 1
    for (int kt = 0; kt < nkv; ++kt) {
      const int kv0 = kt * 64;
      if (kt + 1 < nkv) stage(kt + 1, cur ^ 1);  // prefetch next tile (overlaps compute)
      char* Kt = smem + cur * 8192;
      char* Vt = smem + 16384 + cur * 8192;

      // swapped scores: sw[kf][qf] = K·Q^T ; lane holds q = qf*16+r, kv = kf*16+g*4+reg
      f32x4 sw[4][2] = {};
#pragma unroll
      for (int ks = 0; ks < 2; ++ks) {
        bf16x8 bk[4];
#pragma unroll
        for (int kf = 0; kf < 4; ++kf) {
          int kv = kf * 16 + r;
          int slot = (ks * 4 + g) ^ (kv & 7);
          bk[kf] = *(const bf16x8*)(Kt + kv * 128 + slot * 16);
        }
        __builtin_amdgcn_s_setprio(1);
#pragma unroll
        for (int kf = 0; kf < 4; ++kf)
#pragma unroll
          for (int qf = 0; qf < 2; ++qf)
            sw[kf][qf] = __builtin_amdgcn_mfma_f32_16x16x32_bf16(bk[kf], aq[qf][ks], sw[kf][qf], 0, 0, 0);
        __builtin_amdgcn_s_setprio(0);
      }

      // causal mask (only the two diagonal-adjacent tiles need it)
      if (kt >= 2 * qt) {
#pragma unroll
        for (int kf = 0; kf < 4; ++kf)
#pragma unroll
          for (int qf = 0; qf < 2; ++qf)
#pragma unroll
            for (int reg = 0; reg < 4; ++reg) {
              int qg = qrow0 + qf * 16 + r;
              int kg = kv0 + kf * 16 + g * 4 + reg;
              sw[kf][qf][reg] = (kg > qg) ? -1e30f : sw[kf][qf][reg];
            }
      }

      // tile max per q-row: register fmax chain + 2 shfl
      float tm[2];
#pragma unroll
      for (int qf = 0; qf < 2; ++qf) {
        float t = sw[0][qf][0];
#pragma unroll
        for (int kf = 0; kf < 4; ++kf)
#pragma unroll
          for (int reg = 0; reg < 4; ++reg) t = fmaxf(t, sw[kf][qf][reg]);
        t = fmaxf(t, __shfl_xor(t, 16));
        t = fmaxf(t, __shfl_xor(t, 32));
        tm[qf] = t;
      }

      // defer-max: skip O-rescale when growth small (P bounded by 2^8)
      bool noresc = ((tm[0] - mrow[0]) <= 8.0f) && ((tm[1] - mrow[1]) <= 8.0f);
      if (!__all(noresc)) {
        float scv[2];
#pragma unroll
        for (int qf = 0; qf < 2; ++qf) {
          float mn = fmaxf(mrow[qf], tm[qf]);
          scv[qf] = exp2f(mrow[qf] - mn);
          lrow[qf] *= scv[qf];
          mrow[qf] = mn;
        }
#pragma unroll
        for (int mf = 0; mf < 2; ++mf)
#pragma unroll
          for (int reg = 0; reg < 4; ++reg) {
            float sb = __shfl(scv[mf], ((lane >> 4) << 2) + reg);
#pragma unroll
            for (int db = 0; db < 4; ++db) o[mf][db][reg] *= sb;
          }
      }

      // P = exp2(s - m), row-sum in registers + 2 shfl
      float p[4][2][4];
      float rs[2] = {0.f, 0.f};
#pragma unroll
      for (int kf = 0; kf < 4; ++kf)
#pragma unroll
        for (int qf = 0; qf < 2; ++qf)
#pragma unroll
          for (int reg = 0; reg < 4; ++reg) {
            float pv = exp2f(sw[kf][qf][reg] - mrow[qf]);
            p[kf][qf][reg] = pv;
            rs[qf] += pv;
          }
#pragma unroll
      for (int qf = 0; qf < 2; ++qf) {
        float t = rs[qf];
        t += __shfl_xor(t, 16);
        t += __shfl_xor(t, 32);
        lrow[qf] += t;
      }

      // P -> per-wave LDS: cvt_pk pairs, 8 packed 8-byte writes
#pragma unroll
      for (int qf = 0; qf < 2; ++qf) {
        int row = qf * 16 + r;
        int rbase = row * 128;
        int swz = (row & 7) << 4;
#pragma unroll
        for (int kf = 0; kf < 4; ++kf) {
          int byte = (rbase + kf * 32 + g * 8) ^ swz;
          uint2 w;
          asm("v_cvt_pk_bf16_f32 %0, %1, %2" : "=v"(w.x) : "v"(p[kf][qf][0]), "v"(p[kf][qf][1]));
          asm("v_cvt_pk_bf16_f32 %0, %1, %2" : "=v"(w.y) : "v"(p[kf][qf][2]), "v"(p[kf][qf][3]));
          *(uint2*)(Pl + byte) = w;
        }
      }
      asm volatile("s_waitcnt lgkmcnt(0)" ::: "memory");

      // PV: o[q][d] += P[q][kv] Vt[d][kv]
#pragma unroll
      for (int ks = 0; ks < 2; ++ks) {
        bf16x8 pa[2], bv[4];
#pragma unroll
        for (int mf = 0; mf < 2; ++mf) {
          int row = mf * 16 + r;
          int slot = (ks * 4 + g) ^ (row & 7);
          pa[mf] = *(const bf16x8*)(Pl + row * 128 + slot * 16);
        }
#pragma unroll
        for (int db = 0; db < 4; ++db) {
          int d = db * 16 + r;
          int slot = (ks * 4 + g) ^ (d & 7);
          bv[db] = *(const bf16x8*)(Vt + d * 128 + slot * 16);
        }
        __builtin_amdgcn_s_setprio(1);
#pragma unroll
        for (int mf = 0; mf < 2; ++mf)
#pragma unroll
          for (int db = 0; db < 4; ++db)
            o[mf][db] = __builtin_amdgcn_mfma_f32_16x16x32_bf16(pa[mf], bv[db], o[mf][db], 0, 0, 0);
        __builtin_amdgcn_s_setprio(0);
      }
      __syncthreads();
      cur ^= 1;
    }

    // normalize and write merged-head output [B*S, E] bf16
    const int b_ = bh >> 4, h = bh & 15;
    float invq[2] = {1.f / lrow[0], 1.f / lrow[1]};
#pragma unroll
    for (int mf = 0; mf < 2; ++mf) {
#pragma unroll
      for (int reg = 0; reg < 4; ++reg) {
        float inv = __shfl(invq[mf], ((lane >> 4) << 2) + reg);
        int rowg = b_ * 2048 + qrow0 + mf * 16 + g * 4 + reg;
#pragma unroll
        for (int db = 0; db < 4; ++db) {
          int colg = h * 64 + db * 16 + r;
          aout[(size_t)rowg * 1024 + colg] = f2bf(o[mf][db][reg] * inv);
        }
      }
    }
  }
}

extern "C" void kernel_launch(void* const* d_in, const int* in_sizes, int n_in,
                              void* d_out, int out_size, void* d_ws, size_t ws_size,
                              hipStream_t stream) {
  const float* hs = (const float*)d_in[0];      // [4,2048,1024]
  const float* w_attn = (const float*)d_in[1];  // [1024,3072]
  const float* b_attn = (const float*)d_in[2];  // [3072]
  const float* w_proj = (const float*)d_in[3];  // [1024,1024]
  const float* b_proj = (const float*)d_in[4];  // [1024]
  float* out = (float*)d_out;                   // [4,2048,1024] f32
  char* ws = (char*)d_ws;
  size_t off = 0;
  auto alloc = [&](size_t sz) {
    char* p = ws + off;
    off = (off + sz + 255) & ~(size_t)255;
    return p;
  };
  unsigned short* hs_bf = (unsigned short*)alloc((size_t)8192 * 1024 * 2);
  unsigned short* wattnT = (unsigned short*)alloc((size_t)3072 * 1024 * 2);
  unsigned short* wprojT = (unsigned short*)alloc((size_t)1024 * 1024 * 2);
  unsigned short* qb = (unsigned short*)alloc((size_t)8192 * 1024 * 2);
  unsigned short* kb = (unsigned short*)alloc((size_t)8192 * 1024 * 2);
  unsigned short* vb = (unsigned short*)alloc((size_t)8192 * 1024 * 2);
  unsigned short* vtb = (unsigned short*)alloc((size_t)8192 * 1024 * 2);
  unsigned short* aout = hs_bf;  // hs_bf dead after gemm_qkv; reuse

  cvt_f32_bf16<<<2048, 256, 0, stream>>>(hs, hs_bf, 8192 * 1024 / 4);
  transpose_cvt<<<dim3(48, 16), 256, 0, stream>>>(w_attn, wattnT, 1024, 3072);
  transpose_cvt<<<dim3(16, 16), 256, 0, stream>>>(w_proj, wprojT, 1024, 1024);
  gemm_qkv<<<dim3(12, 32), 512, 0, stream>>>(hs_bf, wattnT, b_attn, qb, kb, vb);
  transpose_b16<<<dim3(1, 32, 64), 256, 0, stream>>>(vb, vtb, 2048, 64);
  attn_kernel<<<dim3(8, 64), 256, 0, stream>>>(qb, kb, vtb, aout);
  gemm_proj<<<dim3(8, 32), 512, 0, stream>>>(aout, wprojT, b_proj, out);
}

// Round 5
// 201.030 us; speedup vs baseline: 1.6779x; 1.0256x over previous
//
#include <hip/hip_runtime.h>
#include <stdint.h>

typedef short bf16x8 __attribute__((ext_vector_type(8)));
typedef float f32x4 __attribute__((ext_vector_type(4)));

__device__ __forceinline__ unsigned short f2bf(float f) {
  unsigned int u = __builtin_bit_cast(unsigned int, f);
  u += 0x7fffu + ((u >> 16) & 1u);
  return (unsigned short)(u >> 16);
}

__device__ __forceinline__ void gload_lds16(const void* g, void* l) {
  __builtin_amdgcn_global_load_lds(
      (const __attribute__((address_space(1))) unsigned int*)g,
      (__attribute__((address_space(3))) unsigned int*)l, 16, 0, 0);
}

// ---------------- elementwise f32 -> bf16 ----------------
__global__ __launch_bounds__(256) void cvt_f32_bf16(const float* __restrict__ in,
                                                    unsigned short* __restrict__ out, int n4) {
  int i = blockIdx.x * blockDim.x + threadIdx.x;
  int stride = gridDim.x * blockDim.x;
  for (; i < n4; i += stride) {
    float4 v = ((const float4*)in)[i];
    ushort4 o;
    o.x = f2bf(v.x); o.y = f2bf(v.y); o.z = f2bf(v.z); o.w = f2bf(v.w);
    ((ushort4*)out)[i] = o;
  }
}

// ---------------- transpose + convert f32[R][C] -> bf16[C][R] ----------------
__global__ __launch_bounds__(256) void transpose_cvt(const float* __restrict__ in,
                                                     unsigned short* __restrict__ out,
                                                     int R, int C) {
  __shared__ unsigned short t[64][65];
  int c0 = blockIdx.x * 64, r0 = blockIdx.y * 64;
  int tid = threadIdx.x;
#pragma unroll
  for (int i = 0; i < 16; ++i) {
    int idx = tid + i * 256;
    int rr = idx >> 6, cc = idx & 63;
    t[rr][cc] = f2bf(in[(size_t)(r0 + rr) * C + c0 + cc]);
  }
  __syncthreads();
#pragma unroll
  for (int i = 0; i < 16; ++i) {
    int idx = tid + i * 256;
    int rr = idx >> 6, cc = idx & 63;
    out[(size_t)(c0 + rr) * R + r0 + cc] = t[cc][rr];
  }
}

// ---------------- batched transpose bf16[z][R][C] -> bf16[z][C][R] ----------------
__global__ __launch_bounds__(256) void transpose_b16(const unsigned short* __restrict__ in,
                                                     unsigned short* __restrict__ out,
                                                     int R, int C) {
  __shared__ unsigned short t[64][65];
  const unsigned short* ip = in + (size_t)blockIdx.z * R * C;
  unsigned short* op = out + (size_t)blockIdx.z * R * C;
  int c0 = blockIdx.x * 64, r0 = blockIdx.y * 64;
  int tid = threadIdx.x;
#pragma unroll
  for (int i = 0; i < 16; ++i) {
    int idx = tid + i * 256;
    int rr = idx >> 6, cc = idx & 63;
    t[rr][cc] = ip[(size_t)(r0 + rr) * C + c0 + cc];
  }
  __syncthreads();
#pragma unroll
  for (int i = 0; i < 16; ++i) {
    int idx = tid + i * 256;
    int rr = idx >> 6, cc = idx & 63;
    op[(size_t)(c0 + rr) * R + r0 + cc] = t[cc][rr];
  }
}

// =========== 256-row 8-wave double-buffered K-loop (BK=64), swizzled LDS ===========
// A [256 rows][ldA] bf16 row-major; Bt [BN rows][ldB] bf16 (output-col major, K contiguous).
// Waves: WN along N (BN/WN cols each), 2 along M (128 rows each). NB = BN/(WN*16) frags.
// LDS: A dbuf 2x32KB @0; B dbuf 2x(BN*128) @65536. XOR-swizzle ((row&7)<<4) on ds_read;
// staged via linear-dest global_load_lds with pre-swizzled source column.
template <int BN, int WN>
__device__ __forceinline__ void kloop256(const unsigned short* __restrict__ Ab,
                                         const unsigned short* __restrict__ Bb,
                                         char* smem, f32x4 (*acc)[BN / (WN * 16)],
                                         int ldA, int ldB) {
  constexpr int MI = 2 * WN;           // m-fragments per wave (wave covers 16*MI rows)
  constexpr int NB = BN / (WN * 16);   // n-fragments per wave
  constexpr int NC = (256 + BN) / 64;  // gload16 calls per K-tile per thread
  constexpr int BUFB = BN * 128;       // bytes per B buffer
  const int tid = threadIdx.x;
  const int lane = tid & 63, wid = tid >> 6;
  const int g = lane >> 4, r = lane & 15;
  const int wr = wid / WN, wc = wid % WN;

  // staging: call c -> LDS linear dest; global source pre-swizzled within the 128B row
  const int srow = (tid >> 3) & 63;  // row within 64-row group
  const int scol = (((tid << 4) & 127) ^ ((srow & 7) << 4)) >> 1;
  const unsigned short* gp[NC];
  int dst[NC];
#pragma unroll
  for (int c = 0; c < NC; ++c) {
    if (c < 4) {
      gp[c] = Ab + (size_t)(c * 64 + srow) * ldA + scol;
      dst[c] = c * 8192 + tid * 16;
    } else {
      gp[c] = Bb + (size_t)((c - 4) * 64 + srow) * ldB + scol;
      dst[c] = 65536 + (c - 4) * 8192 + tid * 16;
    }
  }

  // fragment read offsets (ks=0; ks=1 -> ^64)
  int aoff[MI], boff[NB];
#pragma unroll
  for (int mi = 0; mi < MI; ++mi) {
    int row = wr * (16 * MI) + mi * 16 + r;
    aoff[mi] = row * 128 + ((g * 16) ^ ((row & 7) << 4));
  }
#pragma unroll
  for (int ni = 0; ni < NB; ++ni) {
    int row = wc * (NB * 16) + ni * 16 + r;
    boff[ni] = 65536 + row * 128 + ((g * 16) ^ ((row & 7) << 4));
  }

  int cur = 0;
  // prologue: stage K-tile 0 into buffer 0
#pragma unroll
  for (int c = 0; c < NC; ++c) {
    gload_lds16(gp[c], smem + dst[c]);
    gp[c] += 64;
  }
  __syncthreads();

  for (int kt = 0; kt < 16; ++kt) {
    const int abase = cur * 32768, bbase = cur * BUFB;
    const int nbA = (cur ^ 1) * 32768, nbB = (cur ^ 1) * BUFB;
    const bool pre = (kt < 15);
    bf16x8 bfr[NB];
#pragma unroll
    for (int p = 0; p < 4; ++p) {
      if (pre) {
#pragma unroll
        for (int c = 2 * p; c < 2 * p + 2; ++c)
          if (c < NC) {
            gload_lds16(gp[c], smem + dst[c] + (c < 4 ? nbA : nbB));
            gp[c] += 64;
          }
      }
      const int ks = p >> 1, mh = p & 1;
      const int kx = ks ? 64 : 0;
      if (mh == 0) {
#pragma unroll
        for (int ni = 0; ni < NB; ++ni)
          bfr[ni] = *(const bf16x8*)(smem + ((boff[ni] ^ kx) + bbase));
      }
      bf16x8 afr[MI / 2];
#pragma unroll
      for (int i = 0; i < MI / 2; ++i)
        afr[i] = *(const bf16x8*)(smem + ((aoff[mh * (MI / 2) + i] ^ kx) + abase));
      __builtin_amdgcn_s_setprio(1);
#pragma unroll
      for (int i = 0; i < MI / 2; ++i)
#pragma unroll
        for (int ni = 0; ni < NB; ++ni)
          acc[mh * (MI / 2) + i][ni] =
              __builtin_amdgcn_mfma_f32_16x16x32_bf16(afr[i], bfr[ni], acc[mh * (MI / 2) + i][ni], 0, 0, 0);
      __builtin_amdgcn_s_setprio(0);
    }
    __syncthreads();
    cur ^= 1;
  }
}

// XCD-bijective block swizzle (requires nwg % 8 == 0): same-XCD blocks get
// consecutive linear ids (bn fastest) -> they share the A row-panel in L2.
__device__ __forceinline__ void xcd_swizzle(int gx, int gy, int& bn, int& bm) {
  int orig = blockIdx.y * gx + blockIdx.x;
  int cpx = (gx * gy) >> 3;
  int swz = (orig & 7) * cpx + (orig >> 3);
  bn = swz % gx;
  bm = swz / gx;
}

// ---------------- GEMM1: qkv = hs @ W + b, scatter to q/k/v [B,H,S,D] bf16 ----------------
// tile 256x192, grid 16x32 = 512 blocks = exactly 2 CU-waves
__global__ __launch_bounds__(512, 2) void gemm_qkv(const unsigned short* __restrict__ A,
                                                   const unsigned short* __restrict__ Bt,
                                                   const float* __restrict__ bias,
                                                   unsigned short* __restrict__ qb,
                                                   unsigned short* __restrict__ kb,
                                                   unsigned short* __restrict__ vb) {
  __shared__ __align__(16) char smem[114688];
  const int tid = threadIdx.x;
  const int lane = tid & 63, wid = tid >> 6;
  const int g = lane >> 4, r = lane & 15;
  const int wr = wid >> 2, wc = wid & 3;
  int bn, bm;
  xcd_swizzle(16, 32, bn, bm);
  f32x4 acc[8][3] = {};
  kloop256<192, 4>(A + (size_t)(bm * 256) * 1024, Bt + (size_t)(bn * 192) * 1024, smem, acc, 1024, 1024);

  const int colbase = bn * 192 + wc * 48;
  const int rowbase = bm * 256 + wr * 128;
  const float QSCALE = 0.125f * 1.44269504f;  // fold 1/sqrt(64)*log2(e) into Q
#pragma unroll
  for (int m = 0; m < 8; ++m) {
#pragma unroll
    for (int n = 0; n < 3; ++n) {
#pragma unroll
      for (int reg = 0; reg < 4; ++reg) {
        int gm = rowbase + m * 16 + g * 4 + reg;
        int gn = colbase + n * 16 + r;
        float val = acc[m][n][reg] + bias[gn];
        int sec = gn >> 10;  // 0=q 1=k 2=v (192 !| 1024 -> per element)
        int bb = gm >> 11, s = gm & 2047;
        int hc = gn & 1023;
        int h = hc >> 6, d = hc & 63;
        size_t oidx = (((size_t)(bb * 16 + h)) * 2048 + s) * 64 + d;
        if (sec == 0) qb[oidx] = f2bf(val * QSCALE);
        else if (sec == 1) kb[oidx] = f2bf(val);
        else vb[oidx] = f2bf(val);
      }
    }
  }
}

// ---------------- GEMM2: out = attn_out @ Wp + b (f32 out) ----------------
// tile 256x128, grid 8x32 = 256 blocks = exactly 1 CU-wave
__global__ __launch_bounds__(512, 2) void gemm_proj(const unsigned short* __restrict__ A,
                                                    const unsigned short* __restrict__ Bt,
                                                    const float* __restrict__ bias,
                                                    float* __restrict__ out) {
  __shared__ __align__(16) char smem[98304];
  const int tid = threadIdx.x;
  const int lane = tid & 63, wid = tid >> 6;
  const int g = lane >> 4, r = lane & 15;
  const int wr = wid >> 1, wc = wid & 1;
  int bn, bm;
  xcd_swizzle(8, 32, bn, bm);
  f32x4 acc[4][4] = {};
  kloop256<128, 2>(A + (size_t)(bm * 256) * 1024, Bt + (size_t)(bn * 128) * 1024, smem, acc, 1024, 1024);

  const int colbase = bn * 128 + wc * 64;
  const int rowbase = bm * 256 + wr * 64;
#pragma unroll
  for (int m = 0; m < 4; ++m) {
#pragma unroll
    for (int n = 0; n < 4; ++n) {
#pragma unroll
      for (int reg = 0; reg < 4; ++reg) {
        int gm = rowbase + m * 16 + g * 4 + reg;
        int gn = colbase + n * 16 + r;
        out[(size_t)gm * 1024 + gn] = acc[m][n][reg] + bias[gn];
      }
    }
  }
}

// ---------------- flash attention: swapped QK^T + defer-max ----------------
// q [B,H,S,D] (pre-scaled by 0.125*log2e), k [B,H,S,D], vt [B,H,D,S] -> aout [B*S,E] bf16
// Block bx handles q-tiles {bx, 15-bx} (constant 34 KV-tiles per block).
__global__ __launch_bounds__(256) void attn_kernel(const unsigned short* __restrict__ qb,
                                                   const unsigned short* __restrict__ kb,
                                                   const unsigned short* __restrict__ vtb,
                                                   unsigned short* __restrict__ aout) {
  __shared__ char smem[49152];
  const int tid = threadIdx.x;
  const int wid = tid >> 6, lane = tid & 63;
  const int g = lane >> 4, r = lane & 15;
  const int bx = blockIdx.x, bh = blockIdx.y;
  char* Pl = smem + 32768 + wid * 4096;
  const unsigned short* qbase = qb + (size_t)bh * 2048 * 64;
  const unsigned short* kbh = kb + (size_t)bh * 2048 * 64;
  const unsigned short* vbh = vtb + (size_t)bh * 64 * 2048;

  auto stage = [&](int kt, int cbuf) {
    const int kv0 = kt * 64;
#pragma unroll
    for (int c = 0; c < 2; ++c) {
      int ob = wid * 2048 + c * 1024 + lane * 16;
      int row = ob >> 7;          // 128B per row
      int slot = (ob >> 4) & 7;
      int ss = slot ^ (row & 7);
      gload_lds16(kbh + ((size_t)(kv0 + row)) * 64 + ss * 8,
                  smem + cbuf * 8192 + wid * 2048 + c * 1024);
      gload_lds16(vbh + (size_t)row * 2048 + kv0 + ss * 8,
                  smem + 16384 + cbuf * 8192 + wid * 2048 + c * 1024);
    }
  };

#pragma unroll 1
  for (int pi = 0; pi < 2; ++pi) {
    const int qt = (pi == 0) ? bx : (15 - bx);
    const int qrow0 = qt * 128 + wid * 32;

    bf16x8 aq[2][2];
#pragma unroll
    for (int qf = 0; qf < 2; ++qf)
#pragma unroll
      for (int ks = 0; ks < 2; ++ks)
        aq[qf][ks] = *(const bf16x8*)(qbase + (size_t)(qrow0 + qf * 16 + r) * 64 + ks * 32 + g * 8);

    f32x4 o[2][4] = {};
    float mrow[2] = {-1e30f, -1e30f};
    float lrow[2] = {0.f, 0.f};

    const int nkv = (qt + 1) * 2;
    int cur = 0;
    stage(0, 0);
    __syncthreads();

#pragma unroll 1
    for (int kt = 0; kt < nkv; ++kt) {
      const int kv0 = kt * 64;
      if (kt + 1 < nkv) stage(kt + 1, cur ^ 1);  // prefetch next tile (overlaps compute)
      char* Kt = smem + cur * 8192;
      char* Vt = smem + 16384 + cur * 8192;

      // swapped scores: sw[kf][qf] = K·Q^T ; lane holds q = qf*16+r, kv = kf*16+g*4+reg
      f32x4 sw[4][2] = {};
#pragma unroll
      for (int ks = 0; ks < 2; ++ks) {
        bf16x8 bk[4];
#pragma unroll
        for (int kf = 0; kf < 4; ++kf) {
          int kv = kf * 16 + r;
          int slot = (ks * 4 + g) ^ (kv & 7);
          bk[kf] = *(const bf16x8*)(Kt + kv * 128 + slot * 16);
        }
        __builtin_amdgcn_s_setprio(1);
#pragma unroll
        for (int kf = 0; kf < 4; ++kf)
#pragma unroll
          for (int qf = 0; qf < 2; ++qf)
            sw[kf][qf] = __builtin_amdgcn_mfma_f32_16x16x32_bf16(bk[kf], aq[qf][ks], sw[kf][qf], 0, 0, 0);
        __builtin_amdgcn_s_setprio(0);
      }

      // causal mask (only the two diagonal-adjacent tiles need it)
      if (kt >= 2 * qt) {
#pragma unroll
        for (int kf = 0; kf < 4; ++kf)
#pragma unroll
          for (int qf = 0; qf < 2; ++qf)
#pragma unroll
            for (int reg = 0; reg < 4; ++reg) {
              int qg = qrow0 + qf * 16 + r;
              int kg = kv0 + kf * 16 + g * 4 + reg;
              sw[kf][qf][reg] = (kg > qg) ? -1e30f : sw[kf][qf][reg];
            }
      }

      // tile max per q-row: register fmax chain + 2 shfl
      float tm[2];
#pragma unroll
      for (int qf = 0; qf < 2; ++qf) {
        float t = sw[0][qf][0];
#pragma unroll
        for (int kf = 0; kf < 4; ++kf)
#pragma unroll
          for (int reg = 0; reg < 4; ++reg) t = fmaxf(t, sw[kf][qf][reg]);
        t = fmaxf(t, __shfl_xor(t, 16));
        t = fmaxf(t, __shfl_xor(t, 32));
        tm[qf] = t;
      }

      // defer-max: skip O-rescale when growth small (P bounded by 2^8)
      bool noresc = ((tm[0] - mrow[0]) <= 8.0f) && ((tm[1] - mrow[1]) <= 8.0f);
      if (!__all(noresc)) {
        float scv[2];
#pragma unroll
        for (int qf = 0; qf < 2; ++qf) {
          float mn = fmaxf(mrow[qf], tm[qf]);
          scv[qf] = exp2f(mrow[qf] - mn);
          lrow[qf] *= scv[qf];
          mrow[qf] = mn;
        }
#pragma unroll
        for (int mf = 0; mf < 2; ++mf)
#pragma unroll
          for (int reg = 0; reg < 4; ++reg) {
            float sb = __shfl(scv[mf], ((lane >> 4) << 2) + reg);
#pragma unroll
            for (int db = 0; db < 4; ++db) o[mf][db][reg] *= sb;
          }
      }

      // P = exp2(s - m), row-sum in registers + 2 shfl
      float p[4][2][4];
      float rs[2] = {0.f, 0.f};
#pragma unroll
      for (int kf = 0; kf < 4; ++kf)
#pragma unroll
        for (int qf = 0; qf < 2; ++qf)
#pragma unroll
          for (int reg = 0; reg < 4; ++reg) {
            float pv = exp2f(sw[kf][qf][reg] - mrow[qf]);
            p[kf][qf][reg] = pv;
            rs[qf] += pv;
          }
#pragma unroll
      for (int qf = 0; qf < 2; ++qf) {
        float t = rs[qf];
        t += __shfl_xor(t, 16);
        t += __shfl_xor(t, 32);
        lrow[qf] += t;
      }

      // P -> per-wave LDS: cvt_pk pairs, 8 packed 8-byte writes
#pragma unroll
      for (int qf = 0; qf < 2; ++qf) {
        int row = qf * 16 + r;
        int rbase = row * 128;
        int swz = (row & 7) << 4;
#pragma unroll
        for (int kf = 0; kf < 4; ++kf) {
          int byte = (rbase + kf * 32 + g * 8) ^ swz;
          uint2 w;
          asm("v_cvt_pk_bf16_f32 %0, %1, %2" : "=v"(w.x) : "v"(p[kf][qf][0]), "v"(p[kf][qf][1]));
          asm("v_cvt_pk_bf16_f32 %0, %1, %2" : "=v"(w.y) : "v"(p[kf][qf][2]), "v"(p[kf][qf][3]));
          *(uint2*)(Pl + byte) = w;
        }
      }
      asm volatile("s_waitcnt lgkmcnt(0)" ::: "memory");

      // PV: o[q][d] += P[q][kv] Vt[d][kv]
#pragma unroll
      for (int ks = 0; ks < 2; ++ks) {
        bf16x8 pa[2], bv[4];
#pragma unroll
        for (int mf = 0; mf < 2; ++mf) {
          int row = mf * 16 + r;
          int slot = (ks * 4 + g) ^ (row & 7);
          pa[mf] = *(const bf16x8*)(Pl + row * 128 + slot * 16);
        }
#pragma unroll
        for (int db = 0; db < 4; ++db) {
          int d = db * 16 + r;
          int slot = (ks * 4 + g) ^ (d & 7);
          bv[db] = *(const bf16x8*)(Vt + d * 128 + slot * 16);
        }
        __builtin_amdgcn_s_setprio(1);
#pragma unroll
        for (int mf = 0; mf < 2; ++mf)
#pragma unroll
          for (int db = 0; db < 4; ++db)
            o[mf][db] = __builtin_amdgcn_mfma_f32_16x16x32_bf16(pa[mf], bv[db], o[mf][db], 0, 0, 0);
        __builtin_amdgcn_s_setprio(0);
      }
      __syncthreads();
      cur ^= 1;
    }

    // normalize and write merged-head output [B*S, E] bf16
    const int b_ = bh >> 4, h = bh & 15;
    float invq[2] = {1.f / lrow[0], 1.f / lrow[1]};
#pragma unroll
    for (int mf = 0; mf < 2; ++mf) {
#pragma unroll
      for (int reg = 0; reg < 4; ++reg) {
        float inv = __shfl(invq[mf], ((lane >> 4) << 2) + reg);
        int rowg = b_ * 2048 + qrow0 + mf * 16 + g * 4 + reg;
#pragma unroll
        for (int db = 0; db < 4; ++db) {
          int colg = h * 64 + db * 16 + r;
          aout[(size_t)rowg * 1024 + colg] = f2bf(o[mf][db][reg] * inv);
        }
      }
    }
  }
}

extern "C" void kernel_launch(void* const* d_in, const int* in_sizes, int n_in,
                              void* d_out, int out_size, void* d_ws, size_t ws_size,
                              hipStream_t stream) {
  const float* hs = (const float*)d_in[0];      // [4,2048,1024]
  const float* w_attn = (const float*)d_in[1];  // [1024,3072]
  const float* b_attn = (const float*)d_in[2];  // [3072]
  const float* w_proj = (const float*)d_in[3];  // [1024,1024]
  const float* b_proj = (const float*)d_in[4];  // [1024]
  float* out = (float*)d_out;                   // [4,2048,1024] f32
  char* ws = (char*)d_ws;
  size_t off = 0;
  auto alloc = [&](size_t sz) {
    char* p = ws + off;
    off = (off + sz + 255) & ~(size_t)255;
    return p;
  };
  unsigned short* hs_bf = (unsigned short*)alloc((size_t)8192 * 1024 * 2);
  unsigned short* wattnT = (unsigned short*)alloc((size_t)3072 * 1024 * 2);
  unsigned short* wprojT = (unsigned short*)alloc((size_t)1024 * 1024 * 2);
  unsigned short* qb = (unsigned short*)alloc((size_t)8192 * 1024 * 2);
  unsigned short* kb = (unsigned short*)alloc((size_t)8192 * 1024 * 2);
  unsigned short* vb = (unsigned short*)alloc((size_t)8192 * 1024 * 2);
  unsigned short* vtb = (unsigned short*)alloc((size_t)8192 * 1024 * 2);
  unsigned short* aout = hs_bf;  // hs_bf dead after gemm_qkv; reuse

  cvt_f32_bf16<<<2048, 256, 0, stream>>>(hs, hs_bf, 8192 * 1024 / 4);
  transpose_cvt<<<dim3(48, 16), 256, 0, stream>>>(w_attn, wattnT, 1024, 3072);
  transpose_cvt<<<dim3(16, 16), 256, 0, stream>>>(w_proj, wprojT, 1024, 1024);
  gemm_qkv<<<dim3(16, 32), 512, 0, stream>>>(hs_bf, wattnT, b_attn, qb, kb, vb);
  transpose_b16<<<dim3(1, 32, 64), 256, 0, stream>>>(vb, vtb, 2048, 64);
  attn_kernel<<<dim3(8, 64), 256, 0, stream>>>(qb, kb, vtb, aout);
  gemm_proj<<<dim3(8, 32), 512, 0, stream>>>(aout, wprojT, b_proj, out);
}

// Round 6
// 178.403 us; speedup vs baseline: 1.8907x; 1.1268x over previous
//
#include <hip/hip_runtime.h>
#include <stdint.h>

typedef short bf16x8 __attribute__((ext_vector_type(8)));
typedef float f32x4 __attribute__((ext_vector_type(4)));
typedef float f32x16 __attribute__((ext_vector_type(16)));
typedef unsigned int u32x4 __attribute__((ext_vector_type(4)));

__device__ __forceinline__ unsigned short f2bf(float f) {
  unsigned int u = __builtin_bit_cast(unsigned int, f);
  u += 0x7fffu + ((u >> 16) & 1u);
  return (unsigned short)(u >> 16);
}

__device__ __forceinline__ unsigned int cvtpk(float a, float b) {
  unsigned int r;
  asm("v_cvt_pk_bf16_f32 %0, %1, %2" : "=v"(r) : "v"(a), "v"(b));
  return r;
}

__device__ __forceinline__ void gload_lds16(const void* g, void* l) {
  __builtin_amdgcn_global_load_lds(
      (const __attribute__((address_space(1))) unsigned int*)g,
      (__attribute__((address_space(3))) unsigned int*)l, 16, 0, 0);
}

// ---------------- elementwise f32 -> bf16 ----------------
__global__ __launch_bounds__(256) void cvt_f32_bf16(const float* __restrict__ in,
                                                    unsigned short* __restrict__ out, int n4) {
  int i = blockIdx.x * blockDim.x + threadIdx.x;
  int stride = gridDim.x * blockDim.x;
  for (; i < n4; i += stride) {
    float4 v = ((const float4*)in)[i];
    ushort4 o;
    o.x = f2bf(v.x); o.y = f2bf(v.y); o.z = f2bf(v.z); o.w = f2bf(v.w);
    ((ushort4*)out)[i] = o;
  }
}

// ---------------- transpose + convert f32[R][C] -> bf16[C][R] ----------------
__global__ __launch_bounds__(256) void transpose_cvt(const float* __restrict__ in,
                                                     unsigned short* __restrict__ out,
                                                     int R, int C) {
  __shared__ unsigned short t[64][65];
  int c0 = blockIdx.x * 64, r0 = blockIdx.y * 64;
  int tid = threadIdx.x;
#pragma unroll
  for (int i = 0; i < 16; ++i) {
    int idx = tid + i * 256;
    int rr = idx >> 6, cc = idx & 63;
    t[rr][cc] = f2bf(in[(size_t)(r0 + rr) * C + c0 + cc]);
  }
  __syncthreads();
#pragma unroll
  for (int i = 0; i < 16; ++i) {
    int idx = tid + i * 256;
    int rr = idx >> 6, cc = idx & 63;
    out[(size_t)(c0 + rr) * R + r0 + cc] = t[cc][rr];
  }
}

// ---------------- batched transpose bf16[z][R][C] -> bf16[z][C][R] ----------------
__global__ __launch_bounds__(256) void transpose_b16(const unsigned short* __restrict__ in,
                                                     unsigned short* __restrict__ out,
                                                     int R, int C) {
  __shared__ unsigned short t[64][65];
  const unsigned short* ip = in + (size_t)blockIdx.z * R * C;
  unsigned short* op = out + (size_t)blockIdx.z * R * C;
  int c0 = blockIdx.x * 64, r0 = blockIdx.y * 64;
  int tid = threadIdx.x;
#pragma unroll
  for (int i = 0; i < 16; ++i) {
    int idx = tid + i * 256;
    int rr = idx >> 6, cc = idx & 63;
    t[rr][cc] = ip[(size_t)(r0 + rr) * C + c0 + cc];
  }
  __syncthreads();
#pragma unroll
  for (int i = 0; i < 16; ++i) {
    int idx = tid + i * 256;
    int rr = idx >> 6, cc = idx & 63;
    op[(size_t)(c0 + rr) * R + r0 + cc] = t[cc][rr];
  }
}

// =========== 256-row 8-wave double-buffered K-loop (BK=64), swizzled LDS ===========
template <int BN, int WN>
__device__ __forceinline__ void kloop256(const unsigned short* __restrict__ Ab,
                                         const unsigned short* __restrict__ Bb,
                                         char* smem, f32x4 (*acc)[BN / (WN * 16)],
                                         int ldA, int ldB) {
  constexpr int MI = 2 * WN;
  constexpr int NB = BN / (WN * 16);
  constexpr int NC = (256 + BN) / 64;
  constexpr int BUFB = BN * 128;
  const int tid = threadIdx.x;
  const int lane = tid & 63, wid = tid >> 6;
  const int g = lane >> 4, r = lane & 15;
  const int wr = wid / WN, wc = wid % WN;

  const int srow = (tid >> 3) & 63;
  const int scol = (((tid << 4) & 127) ^ ((srow & 7) << 4)) >> 1;
  const unsigned short* gp[NC];
  int dst[NC];
#pragma unroll
  for (int c = 0; c < NC; ++c) {
    if (c < 4) {
      gp[c] = Ab + (size_t)(c * 64 + srow) * ldA + scol;
      dst[c] = c * 8192 + tid * 16;
    } else {
      gp[c] = Bb + (size_t)((c - 4) * 64 + srow) * ldB + scol;
      dst[c] = 65536 + (c - 4) * 8192 + tid * 16;
    }
  }

  int aoff[MI], boff[NB];
#pragma unroll
  for (int mi = 0; mi < MI; ++mi) {
    int row = wr * (16 * MI) + mi * 16 + r;
    aoff[mi] = row * 128 + ((g * 16) ^ ((row & 7) << 4));
  }
#pragma unroll
  for (int ni = 0; ni < NB; ++ni) {
    int row = wc * (NB * 16) + ni * 16 + r;
    boff[ni] = 65536 + row * 128 + ((g * 16) ^ ((row & 7) << 4));
  }

  int cur = 0;
#pragma unroll
  for (int c = 0; c < NC; ++c) {
    gload_lds16(gp[c], smem + dst[c]);
    gp[c] += 64;
  }
  __syncthreads();

  for (int kt = 0; kt < 16; ++kt) {
    const int abase = cur * 32768, bbase = cur * BUFB;
    const int nbA = (cur ^ 1) * 32768, nbB = (cur ^ 1) * BUFB;
    const bool pre = (kt < 15);
    bf16x8 bfr[NB];
#pragma unroll
    for (int p = 0; p < 4; ++p) {
      if (pre) {
#pragma unroll
        for (int c = 2 * p; c < 2 * p + 2; ++c)
          if (c < NC) {
            gload_lds16(gp[c], smem + dst[c] + (c < 4 ? nbA : nbB));
            gp[c] += 64;
          }
      }
      const int ks = p >> 1, mh = p & 1;
      const int kx = ks ? 64 : 0;
      if (mh == 0) {
#pragma unroll
        for (int ni = 0; ni < NB; ++ni)
          bfr[ni] = *(const bf16x8*)(smem + ((boff[ni] ^ kx) + bbase));
      }
      bf16x8 afr[MI / 2];
#pragma unroll
      for (int i = 0; i < MI / 2; ++i)
        afr[i] = *(const bf16x8*)(smem + ((aoff[mh * (MI / 2) + i] ^ kx) + abase));
      __builtin_amdgcn_s_setprio(1);
#pragma unroll
      for (int i = 0; i < MI / 2; ++i)
#pragma unroll
        for (int ni = 0; ni < NB; ++ni)
          acc[mh * (MI / 2) + i][ni] =
              __builtin_amdgcn_mfma_f32_16x16x32_bf16(afr[i], bfr[ni], acc[mh * (MI / 2) + i][ni], 0, 0, 0);
      __builtin_amdgcn_s_setprio(0);
    }
    __syncthreads();
    cur ^= 1;
  }
}

// XCD-bijective block swizzle (requires nwg % 8 == 0)
__device__ __forceinline__ void xcd_swizzle(int gx, int gy, int& bn, int& bm) {
  int orig = blockIdx.y * gx + blockIdx.x;
  int cpx = (gx * gy) >> 3;
  int swz = (orig & 7) * cpx + (orig >> 3);
  bn = swz % gx;
  bm = swz / gx;
}

// ---------------- GEMM1: qkv = hs @ W + b, scatter to q/k/v [B,H,S,D] bf16 ----------------
__global__ __launch_bounds__(512, 2) void gemm_qkv(const unsigned short* __restrict__ A,
                                                   const unsigned short* __restrict__ Bt,
                                                   const float* __restrict__ bias,
                                                   unsigned short* __restrict__ qb,
                                                   unsigned short* __restrict__ kb,
                                                   unsigned short* __restrict__ vb) {
  __shared__ __align__(16) char smem[114688];
  const int tid = threadIdx.x;
  const int lane = tid & 63, wid = tid >> 6;
  const int g = lane >> 4, r = lane & 15;
  const int wr = wid >> 2, wc = wid & 3;
  int bn, bm;
  xcd_swizzle(16, 32, bn, bm);
  f32x4 acc[8][3] = {};
  kloop256<192, 4>(A + (size_t)(bm * 256) * 1024, Bt + (size_t)(bn * 192) * 1024, smem, acc, 1024, 1024);

  const int colbase = bn * 192 + wc * 48;
  const int rowbase = bm * 256 + wr * 128;
  const float QSCALE = 0.125f * 1.44269504f;
#pragma unroll
  for (int m = 0; m < 8; ++m) {
#pragma unroll
    for (int n = 0; n < 3; ++n) {
#pragma unroll
      for (int reg = 0; reg < 4; ++reg) {
        int gm = rowbase + m * 16 + g * 4 + reg;
        int gn = colbase + n * 16 + r;
        float val = acc[m][n][reg] + bias[gn];
        int sec = gn >> 10;
        int bb = gm >> 11, s = gm & 2047;
        int hc = gn & 1023;
        int h = hc >> 6, d = hc & 63;
        size_t oidx = (((size_t)(bb * 16 + h)) * 2048 + s) * 64 + d;
        if (sec == 0) qb[oidx] = f2bf(val * QSCALE);
        else if (sec == 1) kb[oidx] = f2bf(val);
        else vb[oidx] = f2bf(val);
      }
    }
  }
}

// ---------------- GEMM2: out = attn_out @ Wp + b (f32 out) ----------------
__global__ __launch_bounds__(512, 2) void gemm_proj(const unsigned short* __restrict__ A,
                                                    const unsigned short* __restrict__ Bt,
                                                    const float* __restrict__ bias,
                                                    float* __restrict__ out) {
  __shared__ __align__(16) char smem[98304];
  const int tid = threadIdx.x;
  const int lane = tid & 63, wid = tid >> 6;
  const int g = lane >> 4, r = lane & 15;
  const int wr = wid >> 1, wc = wid & 1;
  int bn, bm;
  xcd_swizzle(8, 32, bn, bm);
  f32x4 acc[4][4] = {};
  kloop256<128, 2>(A + (size_t)(bm * 256) * 1024, Bt + (size_t)(bn * 128) * 1024, smem, acc, 1024, 1024);

  const int colbase = bn * 128 + wc * 64;
  const int rowbase = bm * 256 + wr * 64;
#pragma unroll
  for (int m = 0; m < 4; ++m) {
#pragma unroll
    for (int n = 0; n < 4; ++n) {
#pragma unroll
      for (int reg = 0; reg < 4; ++reg) {
        int gm = rowbase + m * 16 + g * 4 + reg;
        int gn = colbase + n * 16 + r;
        out[(size_t)gm * 1024 + gn] = acc[m][n][reg] + bias[gn];
      }
    }
  }
}

// ---------------- flash attention: 32x32 MFMA, in-register P (cvt_pk+permlane32_swap) ----
// q [B,H,S,D] (pre-scaled by 0.125*log2e), k [B,H,S,D], vt [B,H,D,S] -> aout [B*S,E] bf16
// Block bx handles q-tiles {bx, 15-bx}; each of 4 waves owns 32 q-rows; q = lane&31.
__global__ __launch_bounds__(256) void attn_kernel(const unsigned short* __restrict__ qb,
                                                   const unsigned short* __restrict__ kb,
                                                   const unsigned short* __restrict__ vtb,
                                                   unsigned short* __restrict__ aout) {
  __shared__ char smem[32768];  // K dbuf 2x8KB @0 ; V dbuf 2x8KB @16384
  const int tid = threadIdx.x;
  const int wid = tid >> 6, lane = tid & 63;
  const int c = lane & 31, h = lane >> 5;
  const int bx = blockIdx.x, bh = blockIdx.y;
  const unsigned short* qbase = qb + (size_t)bh * 2048 * 64;
  const unsigned short* kbh = kb + (size_t)bh * 2048 * 64;
  const unsigned short* vbh = vtb + (size_t)bh * 64 * 2048;

  auto stage = [&](int kt, int cbuf) {
    const int kv0 = kt * 64;
#pragma unroll
    for (int cc = 0; cc < 2; ++cc) {
      int ob = wid * 2048 + cc * 1024 + lane * 16;
      int row = ob >> 7;
      int slot = (ob >> 4) & 7;
      int ss = slot ^ (row & 7);
      gload_lds16(kbh + ((size_t)(kv0 + row)) * 64 + ss * 8,
                  smem + cbuf * 8192 + wid * 2048 + cc * 1024);
      gload_lds16(vbh + (size_t)row * 2048 + kv0 + ss * 8,
                  smem + 16384 + cbuf * 8192 + wid * 2048 + cc * 1024);
    }
  };

  // builds the two PV A-frags (k-steps s=0,1 of a 32-kv block) from 16 f32 P values
  auto mkpa = [&](const f32x16& P, bf16x8& paA, bf16x8& paB) {
    unsigned c0 = cvtpk(P[0], P[1]), c2 = cvtpk(P[2], P[3]);
    unsigned c4 = cvtpk(P[4], P[5]), c6 = cvtpk(P[6], P[7]);
    unsigned c8 = cvtpk(P[8], P[9]), c10 = cvtpk(P[10], P[11]);
    unsigned c12 = cvtpk(P[12], P[13]), c14 = cvtpk(P[14], P[15]);
    auto s0 = __builtin_amdgcn_permlane32_swap(c0, c4, false, false);
    auto s1 = __builtin_amdgcn_permlane32_swap(c2, c6, false, false);
    auto s2 = __builtin_amdgcn_permlane32_swap(c8, c12, false, false);
    auto s3 = __builtin_amdgcn_permlane32_swap(c10, c14, false, false);
    u32x4 wA = {s0[0], s1[0], s0[1], s1[1]};
    u32x4 wB = {s2[0], s3[0], s2[1], s3[1]};
    paA = __builtin_bit_cast(bf16x8, wA);
    paB = __builtin_bit_cast(bf16x8, wB);
  };

#pragma unroll 1
  for (int pi = 0; pi < 2; ++pi) {
    const int qt = (pi == 0) ? bx : (15 - bx);
    const int qrow0 = qt * 128 + wid * 32;
    const int qg = qrow0 + c;  // this lane's q-row

    // Q B-frags: aq[ks] = Q[qg][ks*16 + h*8 .. +8]
    bf16x8 aq[4];
#pragma unroll
    for (int ks = 0; ks < 4; ++ks)
      aq[ks] = *(const bf16x8*)(qbase + (size_t)qg * 64 + ks * 16 + h * 8);

    f32x16 o0 = {}, o1 = {};
    float mrow = -1e30f, lrow = 0.f;

    const int nkv = (qt + 1) * 2;
    int cur = 0;
    stage(0, 0);
    __syncthreads();

#pragma unroll 1
    for (int kt = 0; kt < nkv; ++kt) {
      const int kv0 = kt * 64;
      if (kt + 1 < nkv) stage(kt + 1, cur ^ 1);
      char* Kt = smem + cur * 8192;
      char* Vt = smem + 16384 + cur * 8192;

      // QK^T swapped: sw[kb] = mfma32x32(K_block, Q) -> D[kv][q], q = lane&31
      f32x16 sw0 = {}, sw1 = {};
#pragma unroll
      for (int ks = 0; ks < 4; ++ks) {
        const int sl = ((2 * ks + h) ^ (c & 7)) << 4;
        bf16x8 k0 = *(const bf16x8*)(Kt + c * 128 + sl);
        bf16x8 k1 = *(const bf16x8*)(Kt + (32 + c) * 128 + sl);
        __builtin_amdgcn_s_setprio(1);
        sw0 = __builtin_amdgcn_mfma_f32_32x32x16_bf16(k0, aq[ks], sw0, 0, 0, 0);
        sw1 = __builtin_amdgcn_mfma_f32_32x32x16_bf16(k1, aq[ks], sw1, 0, 0, 0);
        __builtin_amdgcn_s_setprio(0);
      }

      // causal mask on the two diagonal-adjacent tiles
      if (kt >= 2 * qt) {
#pragma unroll
        for (int t = 0; t < 16; ++t) {
          int crow = (t & 3) + 8 * (t >> 2) + 4 * h;
          sw0[t] = (kv0 + crow > qg) ? -1e30f : sw0[t];
          sw1[t] = (kv0 + 32 + crow > qg) ? -1e30f : sw1[t];
        }
      }

      // row max: in-register tree + one xor-32 shfl (other half of the row)
      float mx[16];
#pragma unroll
      for (int t = 0; t < 16; ++t) mx[t] = fmaxf(sw0[t], sw1[t]);
#pragma unroll
      for (int s = 8; s > 0; s >>= 1)
#pragma unroll
        for (int t = 0; t < 8; ++t)
          if (t < s) mx[t] = fmaxf(mx[t], mx[t + s]);
      float tm = fmaxf(mx[0], __shfl_xor(mx[0], 32));

      // defer-max: rare rescale (P bounded by 2^8)
      if (!__all(tm - mrow <= 8.0f)) {
        float mn = fmaxf(mrow, tm);
        float sc = __builtin_amdgcn_exp2f(mrow - mn);
        lrow *= sc;
        mrow = mn;
        float sct[16];
#pragma unroll
        for (int t = 0; t < 16; ++t)
          sct[t] = __shfl(sc, (t & 3) + 8 * (t >> 2) + 4 * h);
#pragma unroll
        for (int t = 0; t < 16; ++t) { o0[t] *= sct[t]; o1[t] *= sct[t]; }
      }

      // P = exp2(s - m) in place; row-sum tree + one shfl
      float s_[16];
#pragma unroll
      for (int t = 0; t < 16; ++t) {
        sw0[t] = __builtin_amdgcn_exp2f(sw0[t] - mrow);
        sw1[t] = __builtin_amdgcn_exp2f(sw1[t] - mrow);
        s_[t] = sw0[t] + sw1[t];
      }
#pragma unroll
      for (int s = 8; s > 0; s >>= 1)
#pragma unroll
        for (int t = 0; t < 8; ++t)
          if (t < s) s_[t] += s_[t + s];
      lrow += s_[0] + __shfl_xor(s_[0], 32);

      // P -> bf16 A-frags fully in-register (16 cvt_pk + 8 permlane32_swap)
      bf16x8 pa[4];
      mkpa(sw0, pa[0], pa[1]);
      mkpa(sw1, pa[2], pa[3]);

      // PV: o[db] += P x V ; V B-frag from swizzled V^T LDS
#pragma unroll
      for (int kst = 0; kst < 4; ++kst) {
        const int sl = ((2 * kst + h) ^ (c & 7)) << 4;
        bf16x8 v0 = *(const bf16x8*)(Vt + c * 128 + sl);
        bf16x8 v1 = *(const bf16x8*)(Vt + (32 + c) * 128 + sl);
        __builtin_amdgcn_s_setprio(1);
        o0 = __builtin_amdgcn_mfma_f32_32x32x16_bf16(pa[kst], v0, o0, 0, 0, 0);
        o1 = __builtin_amdgcn_mfma_f32_32x32x16_bf16(pa[kst], v1, o1, 0, 0, 0);
        __builtin_amdgcn_s_setprio(0);
      }
      __syncthreads();
      cur ^= 1;
    }

    // normalize: broadcast 1/l to row owners (16 shfl once per q-tile), write out
    const int b_ = bh >> 4, hh = bh & 15;
    float linv = 1.f / lrow;
    float invt[16];
#pragma unroll
    for (int t = 0; t < 16; ++t)
      invt[t] = __shfl(linv, (t & 3) + 8 * (t >> 2) + 4 * h);
#pragma unroll
    for (int t = 0; t < 16; ++t) {
      int rowg = b_ * 2048 + qrow0 + (t & 3) + 8 * (t >> 2) + 4 * h;
      unsigned short* rp = aout + (size_t)rowg * 1024 + hh * 64;
      rp[c] = f2bf(o0[t] * invt[t]);
      rp[32 + c] = f2bf(o1[t] * invt[t]);
    }
  }
}

extern "C" void kernel_launch(void* const* d_in, const int* in_sizes, int n_in,
                              void* d_out, int out_size, void* d_ws, size_t ws_size,
                              hipStream_t stream) {
  const float* hs = (const float*)d_in[0];      // [4,2048,1024]
  const float* w_attn = (const float*)d_in[1];  // [1024,3072]
  const float* b_attn = (const float*)d_in[2];  // [3072]
  const float* w_proj = (const float*)d_in[3];  // [1024,1024]
  const float* b_proj = (const float*)d_in[4];  // [1024]
  float* out = (float*)d_out;                   // [4,2048,1024] f32
  char* ws = (char*)d_ws;
  size_t off = 0;
  auto alloc = [&](size_t sz) {
    char* p = ws + off;
    off = (off + sz + 255) & ~(size_t)255;
    return p;
  };
  unsigned short* hs_bf = (unsigned short*)alloc((size_t)8192 * 1024 * 2);
  unsigned short* wattnT = (unsigned short*)alloc((size_t)3072 * 1024 * 2);
  unsigned short* wprojT = (unsigned short*)alloc((size_t)1024 * 1024 * 2);
  unsigned short* qb = (unsigned short*)alloc((size_t)8192 * 1024 * 2);
  unsigned short* kbuf = (unsigned short*)alloc((size_t)8192 * 1024 * 2);
  unsigned short* vb = (unsigned short*)alloc((size_t)8192 * 1024 * 2);
  unsigned short* vtb = (unsigned short*)alloc((size_t)8192 * 1024 * 2);
  unsigned short* aout = hs_bf;  // hs_bf dead after gemm_qkv; reuse

  cvt_f32_bf16<<<2048, 256, 0, stream>>>(hs, hs_bf, 8192 * 1024 / 4);
  transpose_cvt<<<dim3(48, 16), 256, 0, stream>>>(w_attn, wattnT, 1024, 3072);
  transpose_cvt<<<dim3(16, 16), 256, 0, stream>>>(w_proj, wprojT, 1024, 1024);
  gemm_qkv<<<dim3(16, 32), 512, 0, stream>>>(hs_bf, wattnT, b_attn, qb, kbuf, vb);
  transpose_b16<<<dim3(1, 32, 64), 256, 0, stream>>>(vb, vtb, 2048, 64);
  attn_kernel<<<dim3(8, 64), 256, 0, stream>>>(qb, kbuf, vtb, aout);
  gemm_proj<<<dim3(8, 32), 512, 0, stream>>>(aout, wprojT, b_proj, out);
}